// Round 3
// baseline (341.684 us; speedup 1.0000x reference)
//
#include <hip/hip_runtime.h>

#define SEQ   1024
#define EMBED 512
#define NHEAD 64
#define HDIM  8
#define MTOT  4096        // BATCH*SEQ
// SCALE * log2(e) folded into qq at kernel-1 epilogue:
#define QPRESCALE 0.5100925247059518f   // (1/sqrt(8)) * 1.4426950408889634

// ---------------------------------------------------------------------------
// Kernel 1: qkv = x @ Wqkv^T  (M=4096, N=1536, K=512), fused quantum epilogue.
// 128x128 tile, 8x8 micro-tile, 8x8 lane grid (both LDS read patterns <=2-way).
// Epilogue: cos(t+theta) cumprod; q additionally prescaled by SCALE*log2e.
// ---------------------------------------------------------------------------
#define QBM 128
#define QBN 128
#define QBK 32

__global__ __launch_bounds__(256)
void qkv_quantum_kernel(const float* __restrict__ x, const float* __restrict__ W,
                        const float* __restrict__ theta,
                        float* __restrict__ qq, float* __restrict__ kq,
                        float* __restrict__ vq)
{
    __shared__ __align__(16) float As[QBK][QBM + 4];
    __shared__ __align__(16) float Bs[QBK][QBN + 4];

    const int tid   = threadIdx.x;
    const int mt    = blockIdx.x & 31;   // m fastest: W panel reuse in L2
    const int nt    = blockIdx.x >> 5;   // 0..11
    const int mbase = mt * QBM;
    const int nbase = nt * QBN;

    // 8x8 lanes within a wave; 4 waves tile 2x2 over the 128x128 block tile.
    const int w  = tid >> 6;
    const int l  = tid & 63;
    const int m0 = (w & 1) * 64 + (l & 7) * 8;
    const int n0 = (w >> 1) * 64 + ((l >> 3) & 7) * 8;

    float acc[8][8];
    #pragma unroll
    for (int i = 0; i < 8; ++i)
        #pragma unroll
        for (int j = 0; j < 8; ++j) acc[i][j] = 0.f;

    for (int k0 = 0; k0 < EMBED; k0 += QBK) {
        #pragma unroll
        for (int p = 0; p < 4; ++p) {            // A: 1024 float4
            const int idx = p * 256 + tid;
            const int r = idx >> 3, c4 = (idx & 7) * 4;
            const float4 v = *(const float4*)(x + (size_t)(mbase + r) * EMBED + k0 + c4);
            As[c4 + 0][r] = v.x; As[c4 + 1][r] = v.y;
            As[c4 + 2][r] = v.z; As[c4 + 3][r] = v.w;
        }
        #pragma unroll
        for (int p = 0; p < 4; ++p) {            // B: 1024 float4
            const int idx = p * 256 + tid;
            const int r = idx >> 3, c4 = (idx & 7) * 4;
            const float4 v = *(const float4*)(W + (size_t)(nbase + r) * EMBED + k0 + c4);
            Bs[c4 + 0][r] = v.x; Bs[c4 + 1][r] = v.y;
            Bs[c4 + 2][r] = v.z; Bs[c4 + 3][r] = v.w;
        }
        __syncthreads();
        #pragma unroll 8
        for (int kk = 0; kk < QBK; ++kk) {
            const float4 a0 = *(const float4*)&As[kk][m0];
            const float4 a1 = *(const float4*)&As[kk][m0 + 4];
            const float4 b0 = *(const float4*)&Bs[kk][n0];
            const float4 b1 = *(const float4*)&Bs[kk][n0 + 4];
            const float a[8] = {a0.x, a0.y, a0.z, a0.w, a1.x, a1.y, a1.z, a1.w};
            const float b[8] = {b0.x, b0.y, b0.z, b0.w, b1.x, b1.y, b1.z, b1.w};
            #pragma unroll
            for (int i = 0; i < 8; ++i)
                #pragma unroll
                for (int j = 0; j < 8; ++j)
                    acc[i][j] = fmaf(a[i], b[j], acc[i][j]);
        }
        __syncthreads();
    }

    // quantum epilogue
    const int ng     = nbase + n0;
    const int seg    = ng >> 9;          // 0=q 1=k 2=v
    const int h      = (ng & 511) >> 3;
    const float qs   = (seg == 0) ? QPRESCALE : 1.0f;
    float th[8];
    #pragma unroll
    for (int d = 0; d < 8; ++d) th[d] = theta[h * 8 + d];
    float* dst = (seg == 0) ? qq : (seg == 1) ? kq : vq;

    #pragma unroll
    for (int i = 0; i < 8; ++i) {
        const int m = mbase + m0 + i;
        const int b = m >> 10;
        const int s = m & (SEQ - 1);
        float cum = 1.f, o[8];
        #pragma unroll
        for (int d = 0; d < 8; ++d) {
            cum *= __cosf(acc[i][d] + th[d]);
            o[d] = cum * qs;
        }
        float* p = dst + ((size_t)(b * NHEAD + h) * SEQ + s) * HDIM;
        *(float4*)(p)     = make_float4(o[0], o[1], o[2], o[3]);
        *(float4*)(p + 4) = make_float4(o[4], o[5], o[6], o[7]);
    }
}

// ---------------------------------------------------------------------------
// Kernel 2: attention. 512 blocks = (b,h) x 2 q-halves -> 2 blocks/CU.
// Wave w owns k-quarter (uniform within wave => broadcast LDS reads, zero
// conflicts). Each thread: 8 q-rows x 256 k-steps. q prescaled => p=exp2(dot).
// 4-way partial combine through LDS (stride 76 to spread banks).
// ---------------------------------------------------------------------------
__global__ __launch_bounds__(256)
void attn_kernel(const float* __restrict__ qq, const float* __restrict__ kq,
                 const float* __restrict__ vq, float* __restrict__ attnbuf)
{
    __shared__ __align__(16) float smem[2 * SEQ * HDIM];   // 64 KB: Ks | Vs
    float* Ks = smem;
    float* Vs = smem + SEQ * HDIM;

    const int tid = threadIdx.x;
    const int bh  = blockIdx.x >> 1;       // b*64 + h
    const int qh  = blockIdx.x & 1;
    const size_t base = (size_t)bh * SEQ * HDIM;

    const float4* ksrc = (const float4*)(kq + base);
    const float4* vsrc = (const float4*)(vq + base);
    #pragma unroll
    for (int i = 0; i < 8; ++i) {          // 2048 float4 each
        ((float4*)Ks)[tid + i * 256] = ksrc[tid + i * 256];
        ((float4*)Vs)[tid + i * 256] = vsrc[tid + i * 256];
    }
    __syncthreads();

    const int ks = tid >> 6;               // wave id = k-quarter (wave-uniform)
    const int rg = tid & 63;
    const int r0 = qh * 512 + rg * 8;

    float q[8][8];
    #pragma unroll
    for (int r = 0; r < 8; ++r) {
        const float* qp = qq + base + (size_t)(r0 + r) * HDIM;
        const float4 v0 = *(const float4*)qp;
        const float4 v1 = *(const float4*)(qp + 4);
        q[r][0] = v0.x; q[r][1] = v0.y; q[r][2] = v0.z; q[r][3] = v0.w;
        q[r][4] = v1.x; q[r][5] = v1.y; q[r][6] = v1.z; q[r][7] = v1.w;
    }

    float den[8];
    float acc[8][8];
    #pragma unroll
    for (int r = 0; r < 8; ++r) {
        den[r] = 0.f;
        #pragma unroll
        for (int d = 0; d < 8; ++d) acc[r][d] = 0.f;
    }

    const float4* kp = (const float4*)(Ks + ks * 256 * HDIM);
    const float4* vp = (const float4*)(Vs + ks * 256 * HDIM);
    #pragma unroll 2
    for (int k = 0; k < 256; ++k) {
        const float4 ka = kp[2 * k], kb = kp[2 * k + 1];
        const float4 va = vp[2 * k], vb = vp[2 * k + 1];
        const float kv[8] = {ka.x, ka.y, ka.z, ka.w, kb.x, kb.y, kb.z, kb.w};
        const float vv[8] = {va.x, va.y, va.z, va.w, vb.x, vb.y, vb.z, vb.w};
        #pragma unroll
        for (int r = 0; r < 8; ++r) {
            float s = q[r][0] * kv[0];
            #pragma unroll
            for (int d = 1; d < 8; ++d) s = fmaf(q[r][d], kv[d], s);
            const float p = __builtin_amdgcn_exp2f(s);   // q prescaled
            den[r] += p;
            #pragma unroll
            for (int d = 0; d < 8; ++d) acc[r][d] = fmaf(p, vv[d], acc[r][d]);
        }
    }

    __syncthreads();            // everyone done with Ks/Vs
    constexpr int CW = 76;      // odd*4 stride spreads banks
    if (ks > 0) {
        float* wp = smem + ((size_t)((ks - 1) * 64 + rg)) * CW;
        #pragma unroll
        for (int r = 0; r < 8; ++r) wp[r] = den[r];
        #pragma unroll
        for (int r = 0; r < 8; ++r)
            #pragma unroll
            for (int d = 0; d < 8; ++d) wp[8 + r * 8 + d] = acc[r][d];
    }
    __syncthreads();
    if (ks == 0) {
        #pragma unroll
        for (int wv = 0; wv < 3; ++wv) {
            const float* wp = smem + ((size_t)(wv * 64 + rg)) * CW;
            #pragma unroll
            for (int r = 0; r < 8; ++r) den[r] += wp[r];
            #pragma unroll
            for (int r = 0; r < 8; ++r)
                #pragma unroll
                for (int d = 0; d < 8; ++d) acc[r][d] += wp[8 + r * 8 + d];
        }
        const int b = bh >> 6, h = bh & 63;
        #pragma unroll
        for (int r = 0; r < 8; ++r) {
            const float inv = 1.f / den[r];
            float o[8];
            #pragma unroll
            for (int d = 0; d < 8; ++d) o[d] = acc[r][d] * inv;
            float* outp = attnbuf + ((size_t)(b * SEQ + r0 + r)) * EMBED + h * HDIM;
            *(float4*)(outp)     = make_float4(o[0], o[1], o[2], o[3]);
            *(float4*)(outp + 4) = make_float4(o[4], o[5], o[6], o[7]);
        }
    }
}

// ---------------------------------------------------------------------------
// Kernel 3: out = attn @ Wout^T + bout   (M=4096, N=512, K=512) — unchanged.
// ---------------------------------------------------------------------------
#define BM 128
#define BN 64
#define BK 32

__global__ __launch_bounds__(256)
void out_gemm_kernel(const float* __restrict__ A, const float* __restrict__ W,
                     const float* __restrict__ bias, float* __restrict__ out)
{
    __shared__ __align__(16) float As[BK][BM + 4];
    __shared__ __align__(16) float Bs[BK][BN + 4];

    const int tid   = threadIdx.x;
    const int mt    = blockIdx.x & 31;
    const int nt    = blockIdx.x >> 5;   // 0..7
    const int mbase = mt * BM;
    const int nbase = nt * BN;

    const int rowg = tid >> 3;
    const int c4   = (tid & 7) << 2;
    const int m0   = (tid >> 3) << 2;
    const int n0   = (tid & 7) << 3;

    float acc[4][8];
    #pragma unroll
    for (int i = 0; i < 4; ++i)
        #pragma unroll
        for (int j = 0; j < 8; ++j) acc[i][j] = 0.f;

    for (int k0 = 0; k0 < EMBED; k0 += BK) {
        #pragma unroll
        for (int p = 0; p < 4; ++p) {
            int r = rowg + p * 32;
            const float4 v = *(const float4*)(A + (size_t)(mbase + r) * EMBED + k0 + c4);
            As[c4 + 0][r] = v.x; As[c4 + 1][r] = v.y;
            As[c4 + 2][r] = v.z; As[c4 + 3][r] = v.w;
        }
        #pragma unroll
        for (int p = 0; p < 2; ++p) {
            int r = rowg + p * 32;
            const float4 v = *(const float4*)(W + (size_t)(nbase + r) * EMBED + k0 + c4);
            Bs[c4 + 0][r] = v.x; Bs[c4 + 1][r] = v.y;
            Bs[c4 + 2][r] = v.z; Bs[c4 + 3][r] = v.w;
        }
        __syncthreads();
        #pragma unroll 8
        for (int kk = 0; kk < BK; ++kk) {
            const float4 a4 = *(const float4*)&As[kk][m0];
            const float4 b0 = *(const float4*)&Bs[kk][n0];
            const float4 b1 = *(const float4*)&Bs[kk][n0 + 4];
            const float a[4] = {a4.x, a4.y, a4.z, a4.w};
            const float b[8] = {b0.x, b0.y, b0.z, b0.w, b1.x, b1.y, b1.z, b1.w};
            #pragma unroll
            for (int i = 0; i < 4; ++i)
                #pragma unroll
                for (int j = 0; j < 8; ++j)
                    acc[i][j] = fmaf(a[i], b[j], acc[i][j]);
        }
        __syncthreads();
    }

    #pragma unroll
    for (int i = 0; i < 4; ++i) {
        const int m = mbase + m0 + i;
        float o[8];
        #pragma unroll
        for (int j = 0; j < 8; ++j) o[j] = acc[i][j] + bias[nbase + n0 + j];
        float* p = out + (size_t)m * EMBED + nbase + n0;
        *(float4*)(p)     = make_float4(o[0], o[1], o[2], o[3]);
        *(float4*)(p + 4) = make_float4(o[4], o[5], o[6], o[7]);
    }
}

// ---------------------------------------------------------------------------
extern "C" void kernel_launch(void* const* d_in, const int* in_sizes, int n_in,
                              void* d_out, int out_size, void* d_ws, size_t ws_size,
                              hipStream_t stream)
{
    const float* x     = (const float*)d_in[0];
    const float* Wqkv  = (const float*)d_in[1];
    const float* Wout  = (const float*)d_in[2];
    const float* bout  = (const float*)d_in[3];
    const float* theta = (const float*)d_in[4];
    float* out = (float*)d_out;

    const size_t per = (size_t)4 * NHEAD * SEQ * HDIM;   // 2,097,152 floats
    float* qq      = (float*)d_ws;
    float* kq      = qq + per;
    float* vq      = kq + per;
    float* attnbuf = vq + per;

    qkv_quantum_kernel<<<dim3(32 * 12), dim3(256), 0, stream>>>(x, Wqkv, theta, qq, kq, vq);
    attn_kernel<<<dim3(512), dim3(256), 0, stream>>>(qq, kq, vq, attnbuf);
    out_gemm_kernel<<<dim3(32 * 8), dim3(256), 0, stream>>>(attnbuf, Wout, bout, out);
}

// Round 4
// 294.740 us; speedup vs baseline: 1.1593x; 1.1593x over previous
//
#include <hip/hip_runtime.h>

#define SEQ   1024
#define EMBED 512
#define NHEAD 64
#define HDIM  8
// (1/sqrt(8)) * log2(e), folded into qq so attn uses raw exp2
#define QPRESCALE 0.5100925247059518f

typedef short bf16x8 __attribute__((ext_vector_type(8)));
typedef float f32x4  __attribute__((ext_vector_type(4)));

__device__ __forceinline__ float u2f(unsigned int u) { union { unsigned int u; float f; } c; c.u = u; return c.f; }
__device__ __forceinline__ unsigned int f2u(float f) { union { float f; unsigned int u; } c; c.f = f; return c.u; }

// ---------------------------------------------------------------------------
// Stage one [128 rows x 64 k] fp32 tile as split-bf16 (hi & lo) into LDS.
// LDS row = 128 B (64 bf16); 16B-block index XOR-swizzled with (row&7) so the
// MFMA fragment reads (16 lanes = 16 rows, same k-block) are conflict-free.
// ---------------------------------------------------------------------------
__device__ __forceinline__ void stage_tile(const float* __restrict__ src,
                                           unsigned char* hiB, unsigned char* loB,
                                           int tid)
{
    #pragma unroll
    for (int p = 0; p < 8; ++p) {
        const int idx = p * 256 + tid;
        const int r = idx >> 4;          // tile row 0..127
        const int q = idx & 15;          // quad of 4 floats along k
        const float4 v = *(const float4*)(src + (size_t)r * EMBED + q * 4);
        const unsigned int b0 = f2u(v.x), b1 = f2u(v.y), b2 = f2u(v.z), b3 = f2u(v.w);
        const unsigned int h01 = (b0 >> 16) | (b1 & 0xFFFF0000u);
        const unsigned int h23 = (b2 >> 16) | (b3 & 0xFFFF0000u);
        const float r0 = v.x - u2f(b0 & 0xFFFF0000u);
        const float r1 = v.y - u2f(b1 & 0xFFFF0000u);
        const float r2 = v.z - u2f(b2 & 0xFFFF0000u);
        const float r3 = v.w - u2f(b3 & 0xFFFF0000u);
        const unsigned int l01 = (f2u(r0) >> 16) | (f2u(r1) & 0xFFFF0000u);
        const unsigned int l23 = (f2u(r2) >> 16) | (f2u(r3) & 0xFFFF0000u);
        const int addr = r * 128 + (((q >> 1) ^ (r & 7)) << 4) + ((q & 1) << 3);
        *(uint2*)(hiB + addr) = make_uint2(h01, h23);
        *(uint2*)(loB + addr) = make_uint2(l01, l23);
    }
}

// ---------------------------------------------------------------------------
// Shared K-loop: C^T[128n x 128m] = A[128n x 512k] * B[128m x 512k]^T via
// split-bf16 3-pass MFMA (hh + lh + hl). 4 waves in a 2x2 grid of 64x64.
// acc[j][i]: j = n-frag, i = m-frag; lane holds col m=(lane&15),
// rows n = j*16 + (lane>>4)*4 + reg.
// ---------------------------------------------------------------------------
__device__ __forceinline__ void gemm_body(const float* __restrict__ A0,
                                          const float* __restrict__ B0,
                                          unsigned char* lds, f32x4 (&acc)[4][4])
{
    unsigned char* Ah = lds;
    unsigned char* Al = lds + 16384;
    unsigned char* Bh = lds + 32768;
    unsigned char* Bl = lds + 49152;
    const int tid  = threadIdx.x;
    const int lane = tid & 63;
    const int w    = tid >> 6;
    const int nw   = (w & 1) * 64;
    const int mw   = (w >> 1) * 64;
    const int col  = lane & 15;
    const int lhi  = lane >> 4;

    for (int k0 = 0; k0 < EMBED; k0 += 64) {
        stage_tile(A0 + k0, Ah, Al, tid);
        stage_tile(B0 + k0, Bh, Bl, tid);
        __syncthreads();
        #pragma unroll
        for (int s = 0; s < 2; ++s) {        // two K=32 steps per BK=64
            bf16x8 ah[4], al[4], bh[4], bl[4];
            #pragma unroll
            for (int j = 0; j < 4; ++j) {
                const int row = nw + j * 16 + col;
                const int addr = row * 128 + (((s * 4 + lhi) ^ (row & 7)) << 4);
                ah[j] = *(const bf16x8*)(Ah + addr);
                al[j] = *(const bf16x8*)(Al + addr);
            }
            #pragma unroll
            for (int i = 0; i < 4; ++i) {
                const int row = mw + i * 16 + col;
                const int addr = row * 128 + (((s * 4 + lhi) ^ (row & 7)) << 4);
                bh[i] = *(const bf16x8*)(Bh + addr);
                bl[i] = *(const bf16x8*)(Bl + addr);
            }
            #pragma unroll
            for (int j = 0; j < 4; ++j)
                #pragma unroll
                for (int i = 0; i < 4; ++i) {
                    acc[j][i] = __builtin_amdgcn_mfma_f32_16x16x32_bf16(ah[j], bh[i], acc[j][i], 0, 0, 0);
                    acc[j][i] = __builtin_amdgcn_mfma_f32_16x16x32_bf16(al[j], bh[i], acc[j][i], 0, 0, 0);
                    acc[j][i] = __builtin_amdgcn_mfma_f32_16x16x32_bf16(ah[j], bl[i], acc[j][i], 0, 0, 0);
                }
        }
        __syncthreads();
    }
}

// ---------------------------------------------------------------------------
// Kernel 1: qkv^T = Wqkv * x^T (split-bf16 MFMA) + quantum epilogue.
// Lane's 4 regs = 4 consecutive n = half a head; one shfl_xor(16) passes the
// d0-3 cumprod to the d4-7 lane. q additionally prescaled by SCALE*log2e.
// ---------------------------------------------------------------------------
__global__ __launch_bounds__(256, 2)
void qkv_mfma_kernel(const float* __restrict__ x, const float* __restrict__ W,
                     const float* __restrict__ theta,
                     float* __restrict__ qq, float* __restrict__ kq,
                     float* __restrict__ vq)
{
    __shared__ __align__(16) unsigned char lds[65536];
    const int nb = blockIdx.x % 12;      // 1536/128
    const int mb = blockIdx.x / 12;      // 4096/128
    const int nbase = nb * 128, mbase = mb * 128;

    f32x4 acc[4][4];
    #pragma unroll
    for (int j = 0; j < 4; ++j)
        #pragma unroll
        for (int i = 0; i < 4; ++i) acc[j][i] = (f32x4)(0.f);

    gemm_body(W + (size_t)nbase * EMBED, x + (size_t)mbase * EMBED, lds, acc);

    const int lane = threadIdx.x & 63;
    const int w    = threadIdx.x >> 6;
    const int nw   = (w & 1) * 64;
    const int mw   = (w >> 1) * 64;
    const int col  = lane & 15;
    const int lhi  = lane >> 4;
    const int dg   = lhi & 1;                 // 0: d0-3, 1: d4-7
    const int seg  = nbase >> 9;              // block-uniform: 0=q 1=k 2=v
    float* dst     = (seg == 0) ? qq : (seg == 1) ? kq : vq;
    const float qs = (seg == 0) ? QPRESCALE : 1.0f;
    const int nseg0 = (nbase & 511) + nw;

    #pragma unroll
    for (int j = 0; j < 4; ++j) {
        const int nq = nseg0 + j * 16 + lhi * 4;   // n within segment (reg 0)
        const int h  = nq >> 3;
        const float4 th = *(const float4*)(theta + h * 8 + dg * 4);
        #pragma unroll
        for (int i = 0; i < 4; ++i) {
            float p0 = __cosf(acc[j][i][0] + th.x);
            float p1 = p0 * __cosf(acc[j][i][1] + th.y);
            float p2 = p1 * __cosf(acc[j][i][2] + th.z);
            float p3 = p2 * __cosf(acc[j][i][3] + th.w);
            const float tot = __shfl_xor(p3, 16);   // partner lane: other half of head
            if (dg) { p0 *= tot; p1 *= tot; p2 *= tot; p3 *= tot; }
            const int m = mbase + mw + i * 16 + col;
            const int b = m >> 10, sidx = m & (SEQ - 1);
            float* pdst = dst + (((size_t)(b * NHEAD + h) * SEQ + sidx) << 3) + dg * 4;
            *(float4*)pdst = make_float4(p0 * qs, p1 * qs, p2 * qs, p3 * qs);
        }
    }
}

// ---------------------------------------------------------------------------
// Kernel 2: attention (unchanged from round 2: 512 blocks, wave-uniform
// k-quarter => broadcast LDS reads, exp2 with prescaled q).
// ---------------------------------------------------------------------------
__global__ __launch_bounds__(256)
void attn_kernel(const float* __restrict__ qq, const float* __restrict__ kq,
                 const float* __restrict__ vq, float* __restrict__ attnbuf)
{
    __shared__ __align__(16) float smem[2 * SEQ * HDIM];   // 64 KB: Ks | Vs
    float* Ks = smem;
    float* Vs = smem + SEQ * HDIM;

    const int tid = threadIdx.x;
    const int bh  = blockIdx.x >> 1;
    const int qh  = blockIdx.x & 1;
    const size_t base = (size_t)bh * SEQ * HDIM;

    const float4* ksrc = (const float4*)(kq + base);
    const float4* vsrc = (const float4*)(vq + base);
    #pragma unroll
    for (int i = 0; i < 8; ++i) {
        ((float4*)Ks)[tid + i * 256] = ksrc[tid + i * 256];
        ((float4*)Vs)[tid + i * 256] = vsrc[tid + i * 256];
    }
    __syncthreads();

    const int ks = tid >> 6;
    const int rg = tid & 63;
    const int r0 = qh * 512 + rg * 8;

    float q[8][8];
    #pragma unroll
    for (int r = 0; r < 8; ++r) {
        const float* qp = qq + base + (size_t)(r0 + r) * HDIM;
        const float4 v0 = *(const float4*)qp;
        const float4 v1 = *(const float4*)(qp + 4);
        q[r][0] = v0.x; q[r][1] = v0.y; q[r][2] = v0.z; q[r][3] = v0.w;
        q[r][4] = v1.x; q[r][5] = v1.y; q[r][6] = v1.z; q[r][7] = v1.w;
    }

    float den[8];
    float acc[8][8];
    #pragma unroll
    for (int r = 0; r < 8; ++r) {
        den[r] = 0.f;
        #pragma unroll
        for (int d = 0; d < 8; ++d) acc[r][d] = 0.f;
    }

    const float4* kp = (const float4*)(Ks + ks * 256 * HDIM);
    const float4* vp = (const float4*)(Vs + ks * 256 * HDIM);
    #pragma unroll 2
    for (int k = 0; k < 256; ++k) {
        const float4 ka = kp[2 * k], kb = kp[2 * k + 1];
        const float4 va = vp[2 * k], vb = vp[2 * k + 1];
        const float kv[8] = {ka.x, ka.y, ka.z, ka.w, kb.x, kb.y, kb.z, kb.w};
        const float vv[8] = {va.x, va.y, va.z, va.w, vb.x, vb.y, vb.z, vb.w};
        #pragma unroll
        for (int r = 0; r < 8; ++r) {
            float s = q[r][0] * kv[0];
            #pragma unroll
            for (int d = 1; d < 8; ++d) s = fmaf(q[r][d], kv[d], s);
            const float p = __builtin_amdgcn_exp2f(s);
            den[r] += p;
            #pragma unroll
            for (int d = 0; d < 8; ++d) acc[r][d] = fmaf(p, vv[d], acc[r][d]);
        }
    }

    __syncthreads();
    constexpr int CW = 76;
    if (ks > 0) {
        float* wp = smem + ((size_t)((ks - 1) * 64 + rg)) * CW;
        #pragma unroll
        for (int r = 0; r < 8; ++r) wp[r] = den[r];
        #pragma unroll
        for (int r = 0; r < 8; ++r)
            #pragma unroll
            for (int d = 0; d < 8; ++d) wp[8 + r * 8 + d] = acc[r][d];
    }
    __syncthreads();
    if (ks == 0) {
        #pragma unroll
        for (int wv = 0; wv < 3; ++wv) {
            const float* wp = smem + ((size_t)(wv * 64 + rg)) * CW;
            #pragma unroll
            for (int r = 0; r < 8; ++r) den[r] += wp[r];
            #pragma unroll
            for (int r = 0; r < 8; ++r)
                #pragma unroll
                for (int d = 0; d < 8; ++d) acc[r][d] += wp[8 + r * 8 + d];
        }
        const int b = bh >> 6, h = bh & 63;
        #pragma unroll
        for (int r = 0; r < 8; ++r) {
            const float inv = 1.f / den[r];
            float o[8];
            #pragma unroll
            for (int d = 0; d < 8; ++d) o[d] = acc[r][d] * inv;
            float* outp = attnbuf + ((size_t)(b * SEQ + r0 + r)) * EMBED + h * HDIM;
            *(float4*)(outp)     = make_float4(o[0], o[1], o[2], o[3]);
            *(float4*)(outp + 4) = make_float4(o[4], o[5], o[6], o[7]);
        }
    }
}

// ---------------------------------------------------------------------------
// Kernel 3: out^T = Wout * attn^T + bout (split-bf16 MFMA). Lane's 4 regs =
// 4 consecutive n => float4 store per (m, n-quad).
// ---------------------------------------------------------------------------
__global__ __launch_bounds__(256, 2)
void out_mfma_kernel(const float* __restrict__ A, const float* __restrict__ W,
                     const float* __restrict__ bias, float* __restrict__ out)
{
    __shared__ __align__(16) unsigned char lds[65536];
    const int nb = blockIdx.x & 3;       // 512/128
    const int mb = blockIdx.x >> 2;      // 4096/128
    const int nbase = nb * 128, mbase = mb * 128;

    f32x4 acc[4][4];
    #pragma unroll
    for (int j = 0; j < 4; ++j)
        #pragma unroll
        for (int i = 0; i < 4; ++i) acc[j][i] = (f32x4)(0.f);

    gemm_body(W + (size_t)nbase * EMBED, A + (size_t)mbase * EMBED, lds, acc);

    const int lane = threadIdx.x & 63;
    const int w    = threadIdx.x >> 6;
    const int nw   = (w & 1) * 64;
    const int mw   = (w >> 1) * 64;
    const int col  = lane & 15;
    const int lhi  = lane >> 4;

    #pragma unroll
    for (int j = 0; j < 4; ++j) {
        const int n0j = nbase + nw + j * 16 + lhi * 4;
        const float4 bs = *(const float4*)(bias + n0j);
        #pragma unroll
        for (int i = 0; i < 4; ++i) {
            const int m = mbase + mw + i * 16 + col;
            float* p = out + (size_t)m * EMBED + n0j;
            *(float4*)p = make_float4(acc[j][i][0] + bs.x, acc[j][i][1] + bs.y,
                                      acc[j][i][2] + bs.z, acc[j][i][3] + bs.w);
        }
    }
}

// ---------------------------------------------------------------------------
extern "C" void kernel_launch(void* const* d_in, const int* in_sizes, int n_in,
                              void* d_out, int out_size, void* d_ws, size_t ws_size,
                              hipStream_t stream)
{
    const float* x     = (const float*)d_in[0];
    const float* Wqkv  = (const float*)d_in[1];
    const float* Wout  = (const float*)d_in[2];
    const float* bout  = (const float*)d_in[3];
    const float* theta = (const float*)d_in[4];
    float* out = (float*)d_out;

    const size_t per = (size_t)4 * NHEAD * SEQ * HDIM;   // 2,097,152 floats
    float* qq      = (float*)d_ws;
    float* kq      = qq + per;
    float* vq      = kq + per;
    float* attnbuf = vq + per;

    qkv_mfma_kernel<<<dim3(12 * 32), dim3(256), 0, stream>>>(x, Wqkv, theta, qq, kq, vq);
    attn_kernel<<<dim3(512), dim3(256), 0, stream>>>(qq, kq, vq, attnbuf);
    out_mfma_kernel<<<dim3(4 * 32), dim3(256), 0, stream>>>(attnbuf, Wout, bout, out);
}

// Round 5
// 248.124 us; speedup vs baseline: 1.3771x; 1.1879x over previous
//
#include <hip/hip_runtime.h>

#define SEQ   1024
#define EMBED 512
#define NHEAD 64
#define HDIM  8
// (1/sqrt(8)) * log2(e), folded into qq so attn uses raw exp2
#define QPRESCALE 0.5100925247059518f

typedef short bf16x8 __attribute__((ext_vector_type(8)));
typedef float f32x4  __attribute__((ext_vector_type(4)));

union B8 { bf16x8 v; unsigned int u[4]; uint2 u2[2]; };

__device__ __forceinline__ float u2f(unsigned int u) { union { unsigned int u; float f; } c; c.u = u; return c.f; }
__device__ __forceinline__ unsigned int f2u(float f) { union { float f; unsigned int u; } c; c.f = f; return c.u; }
// pack two f32 -> bf16 pair (truncation); element 0 in low half
__device__ __forceinline__ unsigned int pk(float e0, float e1) {
    return (f2u(e0) >> 16) | (f2u(e1) & 0xFFFF0000u);
}
__device__ __forceinline__ float tr_hi(float x) { return u2f(f2u(x) & 0xFFFF0000u); }

// ---------------------------------------------------------------------------
// GEMM machinery (kernels 1 & 3) — unchanged from round 4 (verified).
// ---------------------------------------------------------------------------
__device__ __forceinline__ void stage_tile(const float* __restrict__ src,
                                           unsigned char* hiB, unsigned char* loB,
                                           int tid)
{
    #pragma unroll
    for (int p = 0; p < 8; ++p) {
        const int idx = p * 256 + tid;
        const int r = idx >> 4;
        const int q = idx & 15;
        const float4 v = *(const float4*)(src + (size_t)r * EMBED + q * 4);
        const unsigned int b0 = f2u(v.x), b1 = f2u(v.y), b2 = f2u(v.z), b3 = f2u(v.w);
        const unsigned int h01 = (b0 >> 16) | (b1 & 0xFFFF0000u);
        const unsigned int h23 = (b2 >> 16) | (b3 & 0xFFFF0000u);
        const float r0 = v.x - u2f(b0 & 0xFFFF0000u);
        const float r1 = v.y - u2f(b1 & 0xFFFF0000u);
        const float r2 = v.z - u2f(b2 & 0xFFFF0000u);
        const float r3 = v.w - u2f(b3 & 0xFFFF0000u);
        const unsigned int l01 = (f2u(r0) >> 16) | (f2u(r1) & 0xFFFF0000u);
        const unsigned int l23 = (f2u(r2) >> 16) | (f2u(r3) & 0xFFFF0000u);
        const int addr = r * 128 + (((q >> 1) ^ (r & 7)) << 4) + ((q & 1) << 3);
        *(uint2*)(hiB + addr) = make_uint2(h01, h23);
        *(uint2*)(loB + addr) = make_uint2(l01, l23);
    }
}

__device__ __forceinline__ void gemm_body(const float* __restrict__ A0,
                                          const float* __restrict__ B0,
                                          unsigned char* lds, f32x4 (&acc)[4][4])
{
    unsigned char* Ah = lds;
    unsigned char* Al = lds + 16384;
    unsigned char* Bh = lds + 32768;
    unsigned char* Bl = lds + 49152;
    const int tid  = threadIdx.x;
    const int lane = tid & 63;
    const int w    = tid >> 6;
    const int nw   = (w & 1) * 64;
    const int mw   = (w >> 1) * 64;
    const int col  = lane & 15;
    const int lhi  = lane >> 4;

    for (int k0 = 0; k0 < EMBED; k0 += 64) {
        stage_tile(A0 + k0, Ah, Al, tid);
        stage_tile(B0 + k0, Bh, Bl, tid);
        __syncthreads();
        #pragma unroll
        for (int s = 0; s < 2; ++s) {
            bf16x8 ah[4], al[4], bh[4], bl[4];
            #pragma unroll
            for (int j = 0; j < 4; ++j) {
                const int row = nw + j * 16 + col;
                const int addr = row * 128 + (((s * 4 + lhi) ^ (row & 7)) << 4);
                ah[j] = *(const bf16x8*)(Ah + addr);
                al[j] = *(const bf16x8*)(Al + addr);
            }
            #pragma unroll
            for (int i = 0; i < 4; ++i) {
                const int row = mw + i * 16 + col;
                const int addr = row * 128 + (((s * 4 + lhi) ^ (row & 7)) << 4);
                bh[i] = *(const bf16x8*)(Bh + addr);
                bl[i] = *(const bf16x8*)(Bl + addr);
            }
            #pragma unroll
            for (int j = 0; j < 4; ++j)
                #pragma unroll
                for (int i = 0; i < 4; ++i) {
                    acc[j][i] = __builtin_amdgcn_mfma_f32_16x16x32_bf16(ah[j], bh[i], acc[j][i], 0, 0, 0);
                    acc[j][i] = __builtin_amdgcn_mfma_f32_16x16x32_bf16(al[j], bh[i], acc[j][i], 0, 0, 0);
                    acc[j][i] = __builtin_amdgcn_mfma_f32_16x16x32_bf16(ah[j], bl[i], acc[j][i], 0, 0, 0);
                }
        }
        __syncthreads();
    }
}

// ---------------------------------------------------------------------------
// Kernel 1: qkv^T = Wqkv * x^T + quantum epilogue (unchanged, verified).
// ---------------------------------------------------------------------------
__global__ __launch_bounds__(256, 2)
void qkv_mfma_kernel(const float* __restrict__ x, const float* __restrict__ W,
                     const float* __restrict__ theta,
                     float* __restrict__ qq, float* __restrict__ kq,
                     float* __restrict__ vq)
{
    __shared__ __align__(16) unsigned char lds[65536];
    const int nb = blockIdx.x % 12;
    const int mb = blockIdx.x / 12;
    const int nbase = nb * 128, mbase = mb * 128;

    f32x4 acc[4][4];
    #pragma unroll
    for (int j = 0; j < 4; ++j)
        #pragma unroll
        for (int i = 0; i < 4; ++i) acc[j][i] = (f32x4)(0.f);

    gemm_body(W + (size_t)nbase * EMBED, x + (size_t)mbase * EMBED, lds, acc);

    const int lane = threadIdx.x & 63;
    const int w    = threadIdx.x >> 6;
    const int nw   = (w & 1) * 64;
    const int mw   = (w >> 1) * 64;
    const int col  = lane & 15;
    const int lhi  = lane >> 4;
    const int dg   = lhi & 1;
    const int seg  = nbase >> 9;
    float* dst     = (seg == 0) ? qq : (seg == 1) ? kq : vq;
    const float qs = (seg == 0) ? QPRESCALE : 1.0f;
    const int nseg0 = (nbase & 511) + nw;

    #pragma unroll
    for (int j = 0; j < 4; ++j) {
        const int nq = nseg0 + j * 16 + lhi * 4;
        const int h  = nq >> 3;
        const float4 th = *(const float4*)(theta + h * 8 + dg * 4);
        #pragma unroll
        for (int i = 0; i < 4; ++i) {
            float p0 = __cosf(acc[j][i][0] + th.x);
            float p1 = p0 * __cosf(acc[j][i][1] + th.y);
            float p2 = p1 * __cosf(acc[j][i][2] + th.z);
            float p3 = p2 * __cosf(acc[j][i][3] + th.w);
            const float tot = __shfl_xor(p3, 16);
            if (dg) { p0 *= tot; p1 *= tot; p2 *= tot; p3 *= tot; }
            const int m = mbase + mw + i * 16 + col;
            const int b = m >> 10, sidx = m & (SEQ - 1);
            float* pdst = dst + (((size_t)(b * NHEAD + h) * SEQ + sidx) << 3) + dg * 4;
            *(float4*)pdst = make_float4(p0 * qs, p1 * qs, p2 * qs, p3 * qs);
        }
    }
}

// ---------------------------------------------------------------------------
// Kernel 2: MFMA attention, one block per (b,h), 8 waves x 8 q-tiles.
//  QK^T: S^T tile = K_tile x Q_tile with d-split packed into K=32 slots:
//        A(K): [kh,kh,kl,kl], B(Q): [qh,ql,qh,ql]  -> exact (kh+kl)·(qh+ql).
//  P: exp2 on C-frags; slot-group g of the PV B-frag is defined to hold
//     k = {K0+4g..+3} u {K0+16+4g..+3} == this lane's own C-frag regs -> the
//     packed ph/pl feed PV directly, zero cross-lane ops.
//  PV^T: A = [Vh; Vl] stacked in M; passes B=ph, B=pl; shfl_xor(32) combine.
// ---------------------------------------------------------------------------
__global__ __launch_bounds__(512)
void attn_mfma_kernel(const float* __restrict__ qq, const float* __restrict__ kq,
                      const float* __restrict__ vq, float* __restrict__ attnbuf)
{
    __shared__ __align__(16) unsigned char lds[65536];
    unsigned char* Kh = lds;            // [1024][16B] bf16x8 rows (hi)
    unsigned char* Kl = lds + 16384;    // lo
    unsigned char* Vt = lds + 32768;    // [16 rows d-split][2048B], XOR-swizzled

    const int tid = threadIdx.x;
    const int bh  = blockIdx.x;
    const size_t base = (size_t)bh * SEQ * HDIM;

    // ---- stage K as split-bf16 rows ----
    #pragma unroll
    for (int p = 0; p < 2; ++p) {
        const int r = tid + p * 512;
        const float4 a = *(const float4*)(kq + base + (size_t)r * 8);
        const float4 b = *(const float4*)(kq + base + (size_t)r * 8 + 4);
        const unsigned int h0 = pk(tr_hi(a.x), 0.f) | (f2u(a.y) & 0xFFFF0000u);
        // build hi words directly
        const unsigned int hu0 = (f2u(a.x) >> 16) | (f2u(a.y) & 0xFFFF0000u);
        const unsigned int hu1 = (f2u(a.z) >> 16) | (f2u(a.w) & 0xFFFF0000u);
        const unsigned int hu2 = (f2u(b.x) >> 16) | (f2u(b.y) & 0xFFFF0000u);
        const unsigned int hu3 = (f2u(b.z) >> 16) | (f2u(b.w) & 0xFFFF0000u);
        const float r0 = a.x - tr_hi(a.x), r1 = a.y - tr_hi(a.y);
        const float r2 = a.z - tr_hi(a.z), r3 = a.w - tr_hi(a.w);
        const float r4 = b.x - tr_hi(b.x), r5 = b.y - tr_hi(b.y);
        const float r6 = b.z - tr_hi(b.z), r7 = b.w - tr_hi(b.w);
        const unsigned int lu0 = pk(r0, r1), lu1 = pk(r2, r3);
        const unsigned int lu2 = pk(r4, r5), lu3 = pk(r6, r7);
        (void)h0;
        *(uint4*)(Kh + r * 16) = make_uint4(hu0, hu1, hu2, hu3);
        *(uint4*)(Kl + r * 16) = make_uint4(lu0, lu1, lu2, lu3);
    }
    // ---- stage V transposed + split, swizzled ----
    {
        const int k0 = tid * 2;                      // even k; pair (k0, k0+1)
        const float4 va = *(const float4*)(vq + base + (size_t)k0 * 8);
        const float4 vb = *(const float4*)(vq + base + (size_t)k0 * 8 + 4);
        const float4 vc = *(const float4*)(vq + base + (size_t)k0 * 8 + 8);
        const float4 vd = *(const float4*)(vq + base + (size_t)k0 * 8 + 12);
        const float e0[8] = {va.x, va.y, va.z, va.w, vb.x, vb.y, vb.z, vb.w};
        const float e1[8] = {vc.x, vc.y, vc.z, vc.w, vd.x, vd.y, vd.z, vd.w};
        const int blk = k0 >> 3;                     // 16B block in row
        const int byo = (k0 & 7) * 2;
        #pragma unroll
        for (int d = 0; d < 8; ++d) {
            const float h0f = tr_hi(e0[d]), h1f = tr_hi(e1[d]);
            const unsigned int hp = pk(h0f, h1f);
            const unsigned int lp = pk(e0[d] - h0f, e1[d] - h1f);
            const int sb = ((blk ^ (d & 7)) << 4) + byo;
            *(unsigned int*)(Vt + d * 2048 + sb)       = hp;
            *(unsigned int*)(Vt + (d + 8) * 2048 + sb) = lp;
        }
    }
    __syncthreads();

    const int lane = tid & 63;
    const int w    = tid >> 6;           // 0..7
    const int col  = lane & 15;
    const int g    = lane >> 4;          // slot group
    const int bb   = bh >> 6, hh = bh & 63;
    const int koff = (g >= 2) ? 16384 : 0;           // Kh for g<2, Kl for g>=2
    const int vrowbase = col * 2048;
    const int vswz = (col & 7);

    #pragma unroll 1
    for (int it = 0; it < 8; ++it) {
        const int qrow = (w * 8 + it) * 16 + col;    // q within (b,h)
        const float4 qa = *(const float4*)(qq + base + (size_t)qrow * 8);
        const float4 qb = *(const float4*)(qq + base + (size_t)qrow * 8 + 4);
        B8 qh, ql;
        qh.u[0] = (f2u(qa.x) >> 16) | (f2u(qa.y) & 0xFFFF0000u);
        qh.u[1] = (f2u(qa.z) >> 16) | (f2u(qa.w) & 0xFFFF0000u);
        qh.u[2] = (f2u(qb.x) >> 16) | (f2u(qb.y) & 0xFFFF0000u);
        qh.u[3] = (f2u(qb.z) >> 16) | (f2u(qb.w) & 0xFFFF0000u);
        ql.u[0] = pk(qa.x - tr_hi(qa.x), qa.y - tr_hi(qa.y));
        ql.u[1] = pk(qa.z - tr_hi(qa.z), qa.w - tr_hi(qa.w));
        ql.u[2] = pk(qb.x - tr_hi(qb.x), qb.y - tr_hi(qb.y));
        ql.u[3] = pk(qb.z - tr_hi(qb.z), qb.w - tr_hi(qb.w));
        const bf16x8 qfrag = (g & 1) ? ql.v : qh.v;

        f32x4 accO = (f32x4)(0.f);
        float den = 0.f;

        #pragma unroll 2
        for (int ks = 0; ks < 32; ++ks) {
            // --- QK^T: two 16k x 16q tiles (k = ks*32.. and +16) ---
            const bf16x8 ka = *(const bf16x8*)(lds + koff + (size_t)(ks * 32 + col) * 16);
            const bf16x8 kb = *(const bf16x8*)(lds + koff + (size_t)(ks * 32 + 16 + col) * 16);
            f32x4 s0 = __builtin_amdgcn_mfma_f32_16x16x32_bf16(ka, qfrag, (f32x4)(0.f), 0, 0, 0);
            f32x4 s1 = __builtin_amdgcn_mfma_f32_16x16x32_bf16(kb, qfrag, (f32x4)(0.f), 0, 0, 0);
            // --- P = exp2(S) (qq prescaled) ---
            const float p0 = __builtin_amdgcn_exp2f(s0[0]);
            const float p1 = __builtin_amdgcn_exp2f(s0[1]);
            const float p2 = __builtin_amdgcn_exp2f(s0[2]);
            const float p3 = __builtin_amdgcn_exp2f(s0[3]);
            const float p4 = __builtin_amdgcn_exp2f(s1[0]);
            const float p5 = __builtin_amdgcn_exp2f(s1[1]);
            const float p6 = __builtin_amdgcn_exp2f(s1[2]);
            const float p7 = __builtin_amdgcn_exp2f(s1[3]);
            den += ((p0 + p1) + (p2 + p3)) + ((p4 + p5) + (p6 + p7));
            // --- pack ph/pl; this lane's regs ARE its PV B-frag slots ---
            B8 PH, PL;
            PH.u[0] = pk(p0, p1); PH.u[1] = pk(p2, p3);
            PH.u[2] = pk(p4, p5); PH.u[3] = pk(p6, p7);
            PL.u[0] = pk(p0 - tr_hi(p0), p1 - tr_hi(p1));
            PL.u[1] = pk(p2 - tr_hi(p2), p3 - tr_hi(p3));
            PL.u[2] = pk(p4 - tr_hi(p4), p5 - tr_hi(p5));
            PL.u[3] = pk(p6 - tr_hi(p6), p7 - tr_hi(p7));
            // --- V A-frag: slots g hold k = {K0+4g..+3, K0+16+4g..+3} ---
            B8 vf;
            const int b0 = ((ks * 4 + (g >> 1)) ^ vswz) * 16 + (g & 1) * 8;
            const int b1 = ((ks * 4 + 2 + (g >> 1)) ^ vswz) * 16 + (g & 1) * 8;
            vf.u2[0] = *(const uint2*)(Vt + vrowbase + b0);
            vf.u2[1] = *(const uint2*)(Vt + vrowbase + b1);
            accO = __builtin_amdgcn_mfma_f32_16x16x32_bf16(vf.v, PH.v, accO, 0, 0, 0);
            accO = __builtin_amdgcn_mfma_f32_16x16x32_bf16(vf.v, PL.v, accO, 0, 0, 0);
        }

        // --- epilogue: reduce den across g; combine Vh/Vl halves; store ---
        den += __shfl_xor(den, 16);
        den += __shfl_xor(den, 32);
        float o0 = accO[0] + __shfl_xor(accO[0], 32);
        float o1 = accO[1] + __shfl_xor(accO[1], 32);
        float o2 = accO[2] + __shfl_xor(accO[2], 32);
        float o3 = accO[3] + __shfl_xor(accO[3], 32);
        if (g < 2) {
            const float inv = 1.f / den;
            float* outp = attnbuf + ((size_t)(bb * SEQ + qrow)) * EMBED + hh * 8 + g * 4;
            *(float4*)outp = make_float4(o0 * inv, o1 * inv, o2 * inv, o3 * inv);
        }
    }
}

// ---------------------------------------------------------------------------
// Kernel 3: out^T = Wout * attn^T + bout (unchanged, verified).
// ---------------------------------------------------------------------------
__global__ __launch_bounds__(256, 2)
void out_mfma_kernel(const float* __restrict__ A, const float* __restrict__ W,
                     const float* __restrict__ bias, float* __restrict__ out)
{
    __shared__ __align__(16) unsigned char lds[65536];
    const int nb = blockIdx.x & 3;
    const int mb = blockIdx.x >> 2;
    const int nbase = nb * 128, mbase = mb * 128;

    f32x4 acc[4][4];
    #pragma unroll
    for (int j = 0; j < 4; ++j)
        #pragma unroll
        for (int i = 0; i < 4; ++i) acc[j][i] = (f32x4)(0.f);

    gemm_body(W + (size_t)nbase * EMBED, A + (size_t)mbase * EMBED, lds, acc);

    const int lane = threadIdx.x & 63;
    const int w    = threadIdx.x >> 6;
    const int nw   = (w & 1) * 64;
    const int mw   = (w >> 1) * 64;
    const int col  = lane & 15;
    const int lhi  = lane >> 4;

    #pragma unroll
    for (int j = 0; j < 4; ++j) {
        const int n0j = nbase + nw + j * 16 + lhi * 4;
        const float4 bs = *(const float4*)(bias + n0j);
        #pragma unroll
        for (int i = 0; i < 4; ++i) {
            const int m = mbase + mw + i * 16 + col;
            float* p = out + (size_t)m * EMBED + n0j;
            *(float4*)p = make_float4(acc[j][i][0] + bs.x, acc[j][i][1] + bs.y,
                                      acc[j][i][2] + bs.z, acc[j][i][3] + bs.w);
        }
    }
}

// ---------------------------------------------------------------------------
extern "C" void kernel_launch(void* const* d_in, const int* in_sizes, int n_in,
                              void* d_out, int out_size, void* d_ws, size_t ws_size,
                              hipStream_t stream)
{
    const float* x     = (const float*)d_in[0];
    const float* Wqkv  = (const float*)d_in[1];
    const float* Wout  = (const float*)d_in[2];
    const float* bout  = (const float*)d_in[3];
    const float* theta = (const float*)d_in[4];
    float* out = (float*)d_out;

    const size_t per = (size_t)4 * NHEAD * SEQ * HDIM;   // 2,097,152 floats
    float* qq      = (float*)d_ws;
    float* kq      = qq + per;
    float* vq      = kq + per;
    float* attnbuf = vq + per;

    qkv_mfma_kernel<<<dim3(12 * 32), dim3(256), 0, stream>>>(x, Wqkv, theta, qq, kq, vq);
    attn_mfma_kernel<<<dim3(256), dim3(512), 0, stream>>>(qq, kq, vq, attnbuf);
    out_mfma_kernel<<<dim3(4 * 32), dim3(256), 0, stream>>>(attnbuf, Wout, bout, out);
}

// Round 6
// 183.975 us; speedup vs baseline: 1.8572x; 1.3487x over previous
//
#include <hip/hip_runtime.h>

#define SEQ   1024
#define EMBED 512
#define NHEAD 64
#define HDIM  8
// (1/sqrt(8)) * log2(e), folded into qq so attn uses raw exp2
#define QPRESCALE 0.5100925247059518f

typedef short bf16x8 __attribute__((ext_vector_type(8)));
typedef float f32x4  __attribute__((ext_vector_type(4)));

union B8 { bf16x8 v; unsigned int u[4]; uint2 u2[2]; };

__device__ __forceinline__ float u2f(unsigned int u) { union { unsigned int u; float f; } c; c.u = u; return c.f; }
__device__ __forceinline__ unsigned int f2u(float f) { union { float f; unsigned int u; } c; c.f = f; return c.u; }
// pack two f32 -> 2 x bf16 (truncation); element 0 in low half
__device__ __forceinline__ unsigned int pk(float e0, float e1) {
    return (f2u(e0) >> 16) | (f2u(e1) & 0xFFFF0000u);
}
__device__ __forceinline__ float tr_hi(float x) { return u2f(f2u(x) & 0xFFFF0000u); }

// ---------------------------------------------------------------------------
// Prep: split fp32 -> (hi, lo) bf16 planes, once per operand.
// x: 2048 blocks, Wqkv: 768, Wout: 256  (exact, no bounds checks)
// ---------------------------------------------------------------------------
__global__ __launch_bounds__(256)
void split3_kernel(const float* __restrict__ x, const float* __restrict__ wqkv,
                   const float* __restrict__ wout,
                   unsigned short* __restrict__ xh, unsigned short* __restrict__ xl,
                   unsigned short* __restrict__ wqh, unsigned short* __restrict__ wql,
                   unsigned short* __restrict__ woh, unsigned short* __restrict__ wol)
{
    const int b = blockIdx.x;
    const float* src; unsigned short* hi; unsigned short* lo; int i;
    if (b < 2048)      { src = x;    hi = xh;  lo = xl;  i = b * 256 + threadIdx.x; }
    else if (b < 2816) { src = wqkv; hi = wqh; lo = wql; i = (b - 2048) * 256 + threadIdx.x; }
    else               { src = wout; hi = woh; lo = wol; i = (b - 2816) * 256 + threadIdx.x; }
    const float4 v = ((const float4*)src)[i];
    const float h0 = tr_hi(v.x), h1 = tr_hi(v.y), h2 = tr_hi(v.z), h3 = tr_hi(v.w);
    ((uint2*)hi)[i] = make_uint2(pk(v.x, v.y), pk(v.z, v.w));
    ((uint2*)lo)[i] = make_uint2(pk(v.x - h0, v.y - h1), pk(v.z - h2, v.w - h3));
}

// ---------------------------------------------------------------------------
// Plane staging: copy one [128 rows x 64 k] bf16 tile into XOR-swizzled LDS.
// Pure 16B load -> 16B store; LDS physical block s holds global block s^(r&7).
// ---------------------------------------------------------------------------
__device__ __forceinline__ void stage_plane(const unsigned short* __restrict__ plane,
                                            int k0, unsigned char* dst, int tid)
{
    const unsigned char* src = (const unsigned char*)plane + k0 * 2;
    #pragma unroll
    for (int p = 0; p < 4; ++p) {
        const int idx = p * 256 + tid;   // 0..1023 16B-chunks
        const int r = idx >> 3;          // row 0..127
        const int q = idx & 7;           // global 16B block in row-slice
        const uint4 v = *(const uint4*)(src + (size_t)r * 1024 + q * 16);
        *(uint4*)(dst + r * 128 + ((q ^ (r & 7)) << 4)) = v;
    }
}

__device__ __forceinline__ void gemm_body_planes(
    const unsigned short* __restrict__ Ahp, const unsigned short* __restrict__ Alp,
    const unsigned short* __restrict__ Bhp, const unsigned short* __restrict__ Blp,
    unsigned char* lds, f32x4 (&acc)[4][4])
{
    unsigned char* Ah = lds;
    unsigned char* Al = lds + 16384;
    unsigned char* Bh = lds + 32768;
    unsigned char* Bl = lds + 49152;
    const int tid  = threadIdx.x;
    const int lane = tid & 63;
    const int w    = tid >> 6;
    const int nw   = (w & 1) * 64;
    const int mw   = (w >> 1) * 64;
    const int col  = lane & 15;
    const int lhi  = lane >> 4;

    for (int k0 = 0; k0 < EMBED; k0 += 64) {
        stage_plane(Ahp, k0, Ah, tid);
        stage_plane(Alp, k0, Al, tid);
        stage_plane(Bhp, k0, Bh, tid);
        stage_plane(Blp, k0, Bl, tid);
        __syncthreads();
        #pragma unroll
        for (int s = 0; s < 2; ++s) {
            bf16x8 ah[4], al[4], bh[4], bl[4];
            #pragma unroll
            for (int j = 0; j < 4; ++j) {
                const int row = nw + j * 16 + col;
                const int addr = row * 128 + (((s * 4 + lhi) ^ (row & 7)) << 4);
                ah[j] = *(const bf16x8*)(Ah + addr);
                al[j] = *(const bf16x8*)(Al + addr);
            }
            #pragma unroll
            for (int i = 0; i < 4; ++i) {
                const int row = mw + i * 16 + col;
                const int addr = row * 128 + (((s * 4 + lhi) ^ (row & 7)) << 4);
                bh[i] = *(const bf16x8*)(Bh + addr);
                bl[i] = *(const bf16x8*)(Bl + addr);
            }
            #pragma unroll
            for (int j = 0; j < 4; ++j)
                #pragma unroll
                for (int i = 0; i < 4; ++i) {
                    acc[j][i] = __builtin_amdgcn_mfma_f32_16x16x32_bf16(ah[j], bh[i], acc[j][i], 0, 0, 0);
                    acc[j][i] = __builtin_amdgcn_mfma_f32_16x16x32_bf16(al[j], bh[i], acc[j][i], 0, 0, 0);
                    acc[j][i] = __builtin_amdgcn_mfma_f32_16x16x32_bf16(ah[j], bl[i], acc[j][i], 0, 0, 0);
                }
        }
        __syncthreads();
    }
}

// ---------------------------------------------------------------------------
// Kernel 1 (plane path): qkv^T = Wqkv * x^T + quantum epilogue.
// ---------------------------------------------------------------------------
__global__ __launch_bounds__(256, 2)
void qkv_mfma2_kernel(const unsigned short* __restrict__ xh, const unsigned short* __restrict__ xl,
                      const unsigned short* __restrict__ wqh, const unsigned short* __restrict__ wql,
                      const float* __restrict__ theta,
                      float* __restrict__ qq, float* __restrict__ kq,
                      float* __restrict__ vq)
{
    __shared__ __align__(16) unsigned char lds[65536];
    const int nb = blockIdx.x % 12;
    const int mb = blockIdx.x / 12;
    const int nbase = nb * 128, mbase = mb * 128;

    f32x4 acc[4][4];
    #pragma unroll
    for (int j = 0; j < 4; ++j)
        #pragma unroll
        for (int i = 0; i < 4; ++i) acc[j][i] = (f32x4)(0.f);

    gemm_body_planes(wqh + (size_t)nbase * EMBED, wql + (size_t)nbase * EMBED,
                     xh + (size_t)mbase * EMBED, xl + (size_t)mbase * EMBED, lds, acc);

    const int lane = threadIdx.x & 63;
    const int w    = threadIdx.x >> 6;
    const int nw   = (w & 1) * 64;
    const int mw   = (w >> 1) * 64;
    const int col  = lane & 15;
    const int lhi  = lane >> 4;
    const int dg   = lhi & 1;
    const int seg  = nbase >> 9;
    float* dst     = (seg == 0) ? qq : (seg == 1) ? kq : vq;
    const float qs = (seg == 0) ? QPRESCALE : 1.0f;
    const int nseg0 = (nbase & 511) + nw;

    #pragma unroll
    for (int j = 0; j < 4; ++j) {
        const int nq = nseg0 + j * 16 + lhi * 4;
        const int h  = nq >> 3;
        const float4 th = *(const float4*)(theta + h * 8 + dg * 4);
        #pragma unroll
        for (int i = 0; i < 4; ++i) {
            float p0 = __cosf(acc[j][i][0] + th.x);
            float p1 = p0 * __cosf(acc[j][i][1] + th.y);
            float p2 = p1 * __cosf(acc[j][i][2] + th.z);
            float p3 = p2 * __cosf(acc[j][i][3] + th.w);
            const float tot = __shfl_xor(p3, 16);
            if (dg) { p0 *= tot; p1 *= tot; p2 *= tot; p3 *= tot; }
            const int m = mbase + mw + i * 16 + col;
            const int b = m >> 10, sidx = m & (SEQ - 1);
            float* pdst = dst + (((size_t)(b * NHEAD + h) * SEQ + sidx) << 3) + dg * 4;
            *(float4*)pdst = make_float4(p0 * qs, p1 * qs, p2 * qs, p3 * qs);
        }
    }
}

// ---------------------------------------------------------------------------
// Kernel 3 (plane path): out^T = Wout * attn^T + bout.
// ---------------------------------------------------------------------------
__global__ __launch_bounds__(256, 2)
void out_mfma2_kernel(const unsigned short* __restrict__ ath, const unsigned short* __restrict__ atl,
                      const unsigned short* __restrict__ woh, const unsigned short* __restrict__ wol,
                      const float* __restrict__ bias, float* __restrict__ out)
{
    __shared__ __align__(16) unsigned char lds[65536];
    const int nb = blockIdx.x & 3;
    const int mb = blockIdx.x >> 2;
    const int nbase = nb * 128, mbase = mb * 128;

    f32x4 acc[4][4];
    #pragma unroll
    for (int j = 0; j < 4; ++j)
        #pragma unroll
        for (int i = 0; i < 4; ++i) acc[j][i] = (f32x4)(0.f);

    gemm_body_planes(woh + (size_t)nbase * EMBED, wol + (size_t)nbase * EMBED,
                     ath + (size_t)mbase * EMBED, atl + (size_t)mbase * EMBED, lds, acc);

    const int lane = threadIdx.x & 63;
    const int w    = threadIdx.x >> 6;
    const int nw   = (w & 1) * 64;
    const int mw   = (w >> 1) * 64;
    const int col  = lane & 15;
    const int lhi  = lane >> 4;

    #pragma unroll
    for (int j = 0; j < 4; ++j) {
        const int n0j = nbase + nw + j * 16 + lhi * 4;
        const float4 bs = *(const float4*)(bias + n0j);
        #pragma unroll
        for (int i = 0; i < 4; ++i) {
            const int m = mbase + mw + i * 16 + col;
            float* p = out + (size_t)m * EMBED + n0j;
            *(float4*)p = make_float4(acc[j][i][0] + bs.x, acc[j][i][1] + bs.y,
                                      acc[j][i][2] + bs.z, acc[j][i][3] + bs.w);
        }
    }
}

// ---------------------------------------------------------------------------
// Fallback GEMM machinery (round-5, verified) — used when ws_size < 44 MB.
// ---------------------------------------------------------------------------
__device__ __forceinline__ void stage_tile(const float* __restrict__ src,
                                           unsigned char* hiB, unsigned char* loB,
                                           int tid)
{
    #pragma unroll
    for (int p = 0; p < 8; ++p) {
        const int idx = p * 256 + tid;
        const int r = idx >> 4;
        const int q = idx & 15;
        const float4 v = *(const float4*)(src + (size_t)r * EMBED + q * 4);
        const unsigned int b0 = f2u(v.x), b1 = f2u(v.y), b2 = f2u(v.z), b3 = f2u(v.w);
        const unsigned int h01 = (b0 >> 16) | (b1 & 0xFFFF0000u);
        const unsigned int h23 = (b2 >> 16) | (b3 & 0xFFFF0000u);
        const float r0 = v.x - u2f(b0 & 0xFFFF0000u);
        const float r1 = v.y - u2f(b1 & 0xFFFF0000u);
        const float r2 = v.z - u2f(b2 & 0xFFFF0000u);
        const float r3 = v.w - u2f(b3 & 0xFFFF0000u);
        const unsigned int l01 = (f2u(r0) >> 16) | (f2u(r1) & 0xFFFF0000u);
        const unsigned int l23 = (f2u(r2) >> 16) | (f2u(r3) & 0xFFFF0000u);
        const int addr = r * 128 + (((q >> 1) ^ (r & 7)) << 4) + ((q & 1) << 3);
        *(uint2*)(hiB + addr) = make_uint2(h01, h23);
        *(uint2*)(loB + addr) = make_uint2(l01, l23);
    }
}

__device__ __forceinline__ void gemm_body(const float* __restrict__ A0,
                                          const float* __restrict__ B0,
                                          unsigned char* lds, f32x4 (&acc)[4][4])
{
    unsigned char* Ah = lds;
    unsigned char* Al = lds + 16384;
    unsigned char* Bh = lds + 32768;
    unsigned char* Bl = lds + 49152;
    const int tid  = threadIdx.x;
    const int lane = tid & 63;
    const int w    = tid >> 6;
    const int nw   = (w & 1) * 64;
    const int mw   = (w >> 1) * 64;
    const int col  = lane & 15;
    const int lhi  = lane >> 4;

    for (int k0 = 0; k0 < EMBED; k0 += 64) {
        stage_tile(A0 + k0, Ah, Al, tid);
        stage_tile(B0 + k0, Bh, Bl, tid);
        __syncthreads();
        #pragma unroll
        for (int s = 0; s < 2; ++s) {
            bf16x8 ah[4], al[4], bh[4], bl[4];
            #pragma unroll
            for (int j = 0; j < 4; ++j) {
                const int row = nw + j * 16 + col;
                const int addr = row * 128 + (((s * 4 + lhi) ^ (row & 7)) << 4);
                ah[j] = *(const bf16x8*)(Ah + addr);
                al[j] = *(const bf16x8*)(Al + addr);
            }
            #pragma unroll
            for (int i = 0; i < 4; ++i) {
                const int row = mw + i * 16 + col;
                const int addr = row * 128 + (((s * 4 + lhi) ^ (row & 7)) << 4);
                bh[i] = *(const bf16x8*)(Bh + addr);
                bl[i] = *(const bf16x8*)(Bl + addr);
            }
            #pragma unroll
            for (int j = 0; j < 4; ++j)
                #pragma unroll
                for (int i = 0; i < 4; ++i) {
                    acc[j][i] = __builtin_amdgcn_mfma_f32_16x16x32_bf16(ah[j], bh[i], acc[j][i], 0, 0, 0);
                    acc[j][i] = __builtin_amdgcn_mfma_f32_16x16x32_bf16(al[j], bh[i], acc[j][i], 0, 0, 0);
                    acc[j][i] = __builtin_amdgcn_mfma_f32_16x16x32_bf16(ah[j], bl[i], acc[j][i], 0, 0, 0);
                }
        }
        __syncthreads();
    }
}

__global__ __launch_bounds__(256, 2)
void qkv_mfma_kernel(const float* __restrict__ x, const float* __restrict__ W,
                     const float* __restrict__ theta,
                     float* __restrict__ qq, float* __restrict__ kq,
                     float* __restrict__ vq)
{
    __shared__ __align__(16) unsigned char lds[65536];
    const int nb = blockIdx.x % 12;
    const int mb = blockIdx.x / 12;
    const int nbase = nb * 128, mbase = mb * 128;

    f32x4 acc[4][4];
    #pragma unroll
    for (int j = 0; j < 4; ++j)
        #pragma unroll
        for (int i = 0; i < 4; ++i) acc[j][i] = (f32x4)(0.f);

    gemm_body(W + (size_t)nbase * EMBED, x + (size_t)mbase * EMBED, lds, acc);

    const int lane = threadIdx.x & 63;
    const int w    = threadIdx.x >> 6;
    const int nw   = (w & 1) * 64;
    const int mw   = (w >> 1) * 64;
    const int col  = lane & 15;
    const int lhi  = lane >> 4;
    const int dg   = lhi & 1;
    const int seg  = nbase >> 9;
    float* dst     = (seg == 0) ? qq : (seg == 1) ? kq : vq;
    const float qs = (seg == 0) ? QPRESCALE : 1.0f;
    const int nseg0 = (nbase & 511) + nw;

    #pragma unroll
    for (int j = 0; j < 4; ++j) {
        const int nq = nseg0 + j * 16 + lhi * 4;
        const int h  = nq >> 3;
        const float4 th = *(const float4*)(theta + h * 8 + dg * 4);
        #pragma unroll
        for (int i = 0; i < 4; ++i) {
            float p0 = __cosf(acc[j][i][0] + th.x);
            float p1 = p0 * __cosf(acc[j][i][1] + th.y);
            float p2 = p1 * __cosf(acc[j][i][2] + th.z);
            float p3 = p2 * __cosf(acc[j][i][3] + th.w);
            const float tot = __shfl_xor(p3, 16);
            if (dg) { p0 *= tot; p1 *= tot; p2 *= tot; p3 *= tot; }
            const int m = mbase + mw + i * 16 + col;
            const int b = m >> 10, sidx = m & (SEQ - 1);
            float* pdst = dst + (((size_t)(b * NHEAD + h) * SEQ + sidx) << 3) + dg * 4;
            *(float4*)pdst = make_float4(p0 * qs, p1 * qs, p2 * qs, p3 * qs);
        }
    }
}

__global__ __launch_bounds__(256, 2)
void out_mfma_kernel(const float* __restrict__ A, const float* __restrict__ W,
                     const float* __restrict__ bias, float* __restrict__ out)
{
    __shared__ __align__(16) unsigned char lds[65536];
    const int nb = blockIdx.x & 3;
    const int mb = blockIdx.x >> 2;
    const int nbase = nb * 128, mbase = mb * 128;

    f32x4 acc[4][4];
    #pragma unroll
    for (int j = 0; j < 4; ++j)
        #pragma unroll
        for (int i = 0; i < 4; ++i) acc[j][i] = (f32x4)(0.f);

    gemm_body(W + (size_t)nbase * EMBED, A + (size_t)mbase * EMBED, lds, acc);

    const int lane = threadIdx.x & 63;
    const int w    = threadIdx.x >> 6;
    const int nw   = (w & 1) * 64;
    const int mw   = (w >> 1) * 64;
    const int col  = lane & 15;
    const int lhi  = lane >> 4;

    #pragma unroll
    for (int j = 0; j < 4; ++j) {
        const int n0j = nbase + nw + j * 16 + lhi * 4;
        const float4 bs = *(const float4*)(bias + n0j);
        #pragma unroll
        for (int i = 0; i < 4; ++i) {
            const int m = mbase + mw + i * 16 + col;
            float* p = out + (size_t)m * EMBED + n0j;
            *(float4*)p = make_float4(acc[j][i][0] + bs.x, acc[j][i][1] + bs.y,
                                      acc[j][i][2] + bs.z, acc[j][i][3] + bs.w);
        }
    }
}

// ---------------------------------------------------------------------------
// Kernel 2: MFMA attention (round-5 structure). PLANES=1 writes the output as
// split-bf16 hi/lo planes (for out_mfma2); PLANES=0 writes fp32 attnbuf.
// ---------------------------------------------------------------------------
template<int PLANES>
__global__ __launch_bounds__(512)
void attn_mfma_kernel(const float* __restrict__ qq, const float* __restrict__ kq,
                      const float* __restrict__ vq, float* __restrict__ attnbuf,
                      unsigned short* __restrict__ ath, unsigned short* __restrict__ atl)
{
    __shared__ __align__(16) unsigned char lds[65536];
    unsigned char* Kh = lds;            // [1024][16B] bf16x8 rows (hi)
    unsigned char* Kl = lds + 16384;    // lo
    unsigned char* Vt = lds + 32768;    // [16 rows d-split][2048B], XOR-swizzled

    const int tid = threadIdx.x;
    const int bh  = blockIdx.x;
    const size_t base = (size_t)bh * SEQ * HDIM;

    #pragma unroll
    for (int p = 0; p < 2; ++p) {
        const int r = tid + p * 512;
        const float4 a = *(const float4*)(kq + base + (size_t)r * 8);
        const float4 b = *(const float4*)(kq + base + (size_t)r * 8 + 4);
        const unsigned int hu0 = pk(a.x, a.y);
        const unsigned int hu1 = pk(a.z, a.w);
        const unsigned int hu2 = pk(b.x, b.y);
        const unsigned int hu3 = pk(b.z, b.w);
        const unsigned int lu0 = pk(a.x - tr_hi(a.x), a.y - tr_hi(a.y));
        const unsigned int lu1 = pk(a.z - tr_hi(a.z), a.w - tr_hi(a.w));
        const unsigned int lu2 = pk(b.x - tr_hi(b.x), b.y - tr_hi(b.y));
        const unsigned int lu3 = pk(b.z - tr_hi(b.z), b.w - tr_hi(b.w));
        *(uint4*)(Kh + r * 16) = make_uint4(hu0, hu1, hu2, hu3);
        *(uint4*)(Kl + r * 16) = make_uint4(lu0, lu1, lu2, lu3);
    }
    {
        const int k0 = tid * 2;
        const float4 va = *(const float4*)(vq + base + (size_t)k0 * 8);
        const float4 vb = *(const float4*)(vq + base + (size_t)k0 * 8 + 4);
        const float4 vc = *(const float4*)(vq + base + (size_t)k0 * 8 + 8);
        const float4 vd = *(const float4*)(vq + base + (size_t)k0 * 8 + 12);
        const float e0[8] = {va.x, va.y, va.z, va.w, vb.x, vb.y, vb.z, vb.w};
        const float e1[8] = {vc.x, vc.y, vc.z, vc.w, vd.x, vd.y, vd.z, vd.w};
        const int blk = k0 >> 3;
        const int byo = (k0 & 7) * 2;
        #pragma unroll
        for (int d = 0; d < 8; ++d) {
            const float h0f = tr_hi(e0[d]), h1f = tr_hi(e1[d]);
            const unsigned int hp = pk(h0f, h1f);
            const unsigned int lp = pk(e0[d] - h0f, e1[d] - h1f);
            const int sb = ((blk ^ (d & 7)) << 4) + byo;
            *(unsigned int*)(Vt + d * 2048 + sb)       = hp;
            *(unsigned int*)(Vt + (d + 8) * 2048 + sb) = lp;
        }
    }
    __syncthreads();

    const int lane = tid & 63;
    const int w    = tid >> 6;
    const int col  = lane & 15;
    const int g    = lane >> 4;
    const int bb   = bh >> 6, hh = bh & 63;
    const int koff = (g >= 2) ? 16384 : 0;
    const int vrowbase = col * 2048;
    const int vswz = (col & 7);

    #pragma unroll 1
    for (int it = 0; it < 8; ++it) {
        const int qrow = (w * 8 + it) * 16 + col;
        const float4 qa = *(const float4*)(qq + base + (size_t)qrow * 8);
        const float4 qb = *(const float4*)(qq + base + (size_t)qrow * 8 + 4);
        B8 qh, ql;
        qh.u[0] = pk(qa.x, qa.y);
        qh.u[1] = pk(qa.z, qa.w);
        qh.u[2] = pk(qb.x, qb.y);
        qh.u[3] = pk(qb.z, qb.w);
        ql.u[0] = pk(qa.x - tr_hi(qa.x), qa.y - tr_hi(qa.y));
        ql.u[1] = pk(qa.z - tr_hi(qa.z), qa.w - tr_hi(qa.w));
        ql.u[2] = pk(qb.x - tr_hi(qb.x), qb.y - tr_hi(qb.y));
        ql.u[3] = pk(qb.z - tr_hi(qb.z), qb.w - tr_hi(qb.w));
        const bf16x8 qfrag = (g & 1) ? ql.v : qh.v;

        f32x4 accO = (f32x4)(0.f);
        float den = 0.f;

        #pragma unroll 2
        for (int ks = 0; ks < 32; ++ks) {
            const bf16x8 ka = *(const bf16x8*)(lds + koff + (size_t)(ks * 32 + col) * 16);
            const bf16x8 kb = *(const bf16x8*)(lds + koff + (size_t)(ks * 32 + 16 + col) * 16);
            f32x4 s0 = __builtin_amdgcn_mfma_f32_16x16x32_bf16(ka, qfrag, (f32x4)(0.f), 0, 0, 0);
            f32x4 s1 = __builtin_amdgcn_mfma_f32_16x16x32_bf16(kb, qfrag, (f32x4)(0.f), 0, 0, 0);
            const float p0 = __builtin_amdgcn_exp2f(s0[0]);
            const float p1 = __builtin_amdgcn_exp2f(s0[1]);
            const float p2 = __builtin_amdgcn_exp2f(s0[2]);
            const float p3 = __builtin_amdgcn_exp2f(s0[3]);
            const float p4 = __builtin_amdgcn_exp2f(s1[0]);
            const float p5 = __builtin_amdgcn_exp2f(s1[1]);
            const float p6 = __builtin_amdgcn_exp2f(s1[2]);
            const float p7 = __builtin_amdgcn_exp2f(s1[3]);
            den += ((p0 + p1) + (p2 + p3)) + ((p4 + p5) + (p6 + p7));
            B8 PH, PL;
            PH.u[0] = pk(p0, p1); PH.u[1] = pk(p2, p3);
            PH.u[2] = pk(p4, p5); PH.u[3] = pk(p6, p7);
            PL.u[0] = pk(p0 - tr_hi(p0), p1 - tr_hi(p1));
            PL.u[1] = pk(p2 - tr_hi(p2), p3 - tr_hi(p3));
            PL.u[2] = pk(p4 - tr_hi(p4), p5 - tr_hi(p5));
            PL.u[3] = pk(p6 - tr_hi(p6), p7 - tr_hi(p7));
            B8 vf;
            const int b0 = ((ks * 4 + (g >> 1)) ^ vswz) * 16 + (g & 1) * 8;
            const int b1 = ((ks * 4 + 2 + (g >> 1)) ^ vswz) * 16 + (g & 1) * 8;
            vf.u2[0] = *(const uint2*)(Vt + vrowbase + b0);
            vf.u2[1] = *(const uint2*)(Vt + vrowbase + b1);
            accO = __builtin_amdgcn_mfma_f32_16x16x32_bf16(vf.v, PH.v, accO, 0, 0, 0);
            accO = __builtin_amdgcn_mfma_f32_16x16x32_bf16(vf.v, PL.v, accO, 0, 0, 0);
        }

        den += __shfl_xor(den, 16);
        den += __shfl_xor(den, 32);
        float o0 = accO[0] + __shfl_xor(accO[0], 32);
        float o1 = accO[1] + __shfl_xor(accO[1], 32);
        float o2 = accO[2] + __shfl_xor(accO[2], 32);
        float o3 = accO[3] + __shfl_xor(accO[3], 32);
        if (g < 2) {
            const float inv = 1.f / den;
            const float s0 = o0 * inv, s1 = o1 * inv, s2 = o2 * inv, s3 = o3 * inv;
            const size_t off = ((size_t)(bb * SEQ + qrow)) * EMBED + hh * 8 + g * 4;
            if (PLANES) {
                const float h0 = tr_hi(s0), h1 = tr_hi(s1), h2 = tr_hi(s2), h3 = tr_hi(s3);
                *(uint2*)(ath + off) = make_uint2(pk(s0, s1), pk(s2, s3));
                *(uint2*)(atl + off) = make_uint2(pk(s0 - h0, s1 - h1), pk(s2 - h2, s3 - h3));
            } else {
                *(float4*)(attnbuf + off) = make_float4(s0, s1, s2, s3);
            }
        }
    }
}

// ---------------------------------------------------------------------------
extern "C" void kernel_launch(void* const* d_in, const int* in_sizes, int n_in,
                              void* d_out, int out_size, void* d_ws, size_t ws_size,
                              hipStream_t stream)
{
    const float* x     = (const float*)d_in[0];
    const float* Wqkv  = (const float*)d_in[1];
    const float* Wout  = (const float*)d_in[2];
    const float* bout  = (const float*)d_in[3];
    const float* theta = (const float*)d_in[4];
    float* out = (float*)d_out;

    const size_t per = (size_t)4 * NHEAD * SEQ * HDIM;   // 2,097,152
    float* qq = (float*)d_ws;
    float* kq = qq + per;
    float* vq = kq + per;

    const size_t NEED = 46137344;   // 44 MB
    if (ws_size >= NEED) {
        unsigned short* xh  = (unsigned short*)(vq + per);
        unsigned short* xl  = xh + per;               // x: 2,097,152 elems
        unsigned short* wqh = xl + per;
        unsigned short* wql = wqh + 786432;           // Wqkv: 786,432
        unsigned short* woh = wql + 786432;
        unsigned short* wol = woh + 262144;           // Wout: 262,144
        unsigned short* ath = wol + 262144;
        unsigned short* atl = ath + per;              // attn out: 2,097,152

        split3_kernel<<<dim3(3072), dim3(256), 0, stream>>>(x, Wqkv, Wout,
                                                            xh, xl, wqh, wql, woh, wol);
        qkv_mfma2_kernel<<<dim3(384), dim3(256), 0, stream>>>(xh, xl, wqh, wql, theta, qq, kq, vq);
        attn_mfma_kernel<1><<<dim3(256), dim3(512), 0, stream>>>(qq, kq, vq, nullptr, ath, atl);
        out_mfma2_kernel<<<dim3(128), dim3(256), 0, stream>>>(ath, atl, woh, wol, bout, out);
    } else {
        float* attnbuf = vq + per;
        qkv_mfma_kernel<<<dim3(384), dim3(256), 0, stream>>>(x, Wqkv, theta, qq, kq, vq);
        attn_mfma_kernel<0><<<dim3(256), dim3(512), 0, stream>>>(qq, kq, vq, attnbuf, nullptr, nullptr);
        out_mfma_kernel<<<dim3(128), dim3(256), 0, stream>>>(attnbuf, Wout, bout, out);
    }
}

// Round 9
// 163.053 us; speedup vs baseline: 2.0955x; 1.1283x over previous
//
#include <hip/hip_runtime.h>

#define SEQ   1024
#define EMBED 512
#define NHEAD 64
#define HDIM  8
// (1/sqrt(8)) * log2(e), folded into qq so attn uses raw exp2
#define QPRESCALE 0.5100925247059518f

typedef short bf16x8 __attribute__((ext_vector_type(8)));
typedef float f32x4  __attribute__((ext_vector_type(4)));

union B8 { bf16x8 v; unsigned int u[4]; uint2 u2[2]; };

__device__ __forceinline__ float u2f(unsigned int u) { union { unsigned int u; float f; } c; c.u = u; return c.f; }
__device__ __forceinline__ unsigned int f2u(float f) { union { float f; unsigned int u; } c; c.f = f; return c.u; }
// pack two f32 -> 2 x bf16 (truncation); element 0 in low half
__device__ __forceinline__ unsigned int pk(float e0, float e1) {
    return (f2u(e0) >> 16) | (f2u(e1) & 0xFFFF0000u);
}
__device__ __forceinline__ float tr_hi(float x) { return u2f(f2u(x) & 0xFFFF0000u); }

// ---------------------------------------------------------------------------
// Prep: split fp32 -> (hi, lo) bf16 planes, once per operand.
// ---------------------------------------------------------------------------
__global__ __launch_bounds__(256)
void split3_kernel(const float* __restrict__ x, const float* __restrict__ wqkv,
                   const float* __restrict__ wout,
                   unsigned short* __restrict__ xh, unsigned short* __restrict__ xl,
                   unsigned short* __restrict__ wqh, unsigned short* __restrict__ wql,
                   unsigned short* __restrict__ woh, unsigned short* __restrict__ wol)
{
    const int b = blockIdx.x;
    const float* src; unsigned short* hi; unsigned short* lo; int i;
    if (b < 2048)      { src = x;    hi = xh;  lo = xl;  i = b * 256 + threadIdx.x; }
    else if (b < 2816) { src = wqkv; hi = wqh; lo = wql; i = (b - 2048) * 256 + threadIdx.x; }
    else               { src = wout; hi = woh; lo = wol; i = (b - 2816) * 256 + threadIdx.x; }
    const float4 v = ((const float4*)src)[i];
    const float h0 = tr_hi(v.x), h1 = tr_hi(v.y), h2 = tr_hi(v.z), h3 = tr_hi(v.w);
    ((uint2*)hi)[i] = make_uint2(pk(v.x, v.y), pk(v.z, v.w));
    ((uint2*)lo)[i] = make_uint2(pk(v.x - h0, v.y - h1), pk(v.z - h2, v.w - h3));
}

// ---------------------------------------------------------------------------
// Plane staging for GEMMs (verified round 6).
// ---------------------------------------------------------------------------
__device__ __forceinline__ void stage_plane(const unsigned short* __restrict__ plane,
                                            int k0, unsigned char* dst, int tid)
{
    const unsigned char* src = (const unsigned char*)plane + k0 * 2;
    #pragma unroll
    for (int p = 0; p < 4; ++p) {
        const int idx = p * 256 + tid;
        const int r = idx >> 3;
        const int q = idx & 7;
        const uint4 v = *(const uint4*)(src + (size_t)r * 1024 + q * 16);
        *(uint4*)(dst + r * 128 + ((q ^ (r & 7)) << 4)) = v;
    }
}

__device__ __forceinline__ void gemm_body_planes(
    const unsigned short* __restrict__ Ahp, const unsigned short* __restrict__ Alp,
    const unsigned short* __restrict__ Bhp, const unsigned short* __restrict__ Blp,
    unsigned char* lds, f32x4 (&acc)[4][4])
{
    unsigned char* Ah = lds;
    unsigned char* Al = lds + 16384;
    unsigned char* Bh = lds + 32768;
    unsigned char* Bl = lds + 49152;
    const int tid  = threadIdx.x;
    const int lane = tid & 63;
    const int w    = tid >> 6;
    const int nw   = (w & 1) * 64;
    const int mw   = (w >> 1) * 64;
    const int col  = lane & 15;
    const int lhi  = lane >> 4;

    for (int k0 = 0; k0 < EMBED; k0 += 64) {
        stage_plane(Ahp, k0, Ah, tid);
        stage_plane(Alp, k0, Al, tid);
        stage_plane(Bhp, k0, Bh, tid);
        stage_plane(Blp, k0, Bl, tid);
        __syncthreads();
        #pragma unroll
        for (int s = 0; s < 2; ++s) {
            bf16x8 ah[4], al[4], bh[4], bl[4];
            #pragma unroll
            for (int j = 0; j < 4; ++j) {
                const int row = nw + j * 16 + col;
                const int addr = row * 128 + (((s * 4 + lhi) ^ (row & 7)) << 4);
                ah[j] = *(const bf16x8*)(Ah + addr);
                al[j] = *(const bf16x8*)(Al + addr);
            }
            #pragma unroll
            for (int i = 0; i < 4; ++i) {
                const int row = mw + i * 16 + col;
                const int addr = row * 128 + (((s * 4 + lhi) ^ (row & 7)) << 4);
                bh[i] = *(const bf16x8*)(Bh + addr);
                bl[i] = *(const bf16x8*)(Bl + addr);
            }
            #pragma unroll
            for (int j = 0; j < 4; ++j)
                #pragma unroll
                for (int i = 0; i < 4; ++i) {
                    acc[j][i] = __builtin_amdgcn_mfma_f32_16x16x32_bf16(ah[j], bh[i], acc[j][i], 0, 0, 0);
                    acc[j][i] = __builtin_amdgcn_mfma_f32_16x16x32_bf16(al[j], bh[i], acc[j][i], 0, 0, 0);
                    acc[j][i] = __builtin_amdgcn_mfma_f32_16x16x32_bf16(ah[j], bl[i], acc[j][i], 0, 0, 0);
                }
        }
        __syncthreads();
    }
}

// ---------------------------------------------------------------------------
// Kernel 1 (plane path): qkv^T = Wqkv * x^T + quantum epilogue.
// ---------------------------------------------------------------------------
__global__ __launch_bounds__(256, 2)
void qkv_mfma2_kernel(const unsigned short* __restrict__ xh, const unsigned short* __restrict__ xl,
                      const unsigned short* __restrict__ wqh, const unsigned short* __restrict__ wql,
                      const float* __restrict__ theta,
                      float* __restrict__ qq, float* __restrict__ kq,
                      float* __restrict__ vq)
{
    __shared__ __align__(16) unsigned char lds[65536];
    const int nb = blockIdx.x % 12;
    const int mb = blockIdx.x / 12;
    const int nbase = nb * 128, mbase = mb * 128;

    f32x4 acc[4][4];
    #pragma unroll
    for (int j = 0; j < 4; ++j)
        #pragma unroll
        for (int i = 0; i < 4; ++i) acc[j][i] = (f32x4)(0.f);

    gemm_body_planes(wqh + (size_t)nbase * EMBED, wql + (size_t)nbase * EMBED,
                     xh + (size_t)mbase * EMBED, xl + (size_t)mbase * EMBED, lds, acc);

    const int lane = threadIdx.x & 63;
    const int w    = threadIdx.x >> 6;
    const int nw   = (w & 1) * 64;
    const int mw   = (w >> 1) * 64;
    const int col  = lane & 15;
    const int lhi  = lane >> 4;
    const int dg   = lhi & 1;
    const int seg  = nbase >> 9;
    float* dst     = (seg == 0) ? qq : (seg == 1) ? kq : vq;
    const float qs = (seg == 0) ? QPRESCALE : 1.0f;
    const int nseg0 = (nbase & 511) + nw;

    #pragma unroll
    for (int j = 0; j < 4; ++j) {
        const int nq = nseg0 + j * 16 + lhi * 4;
        const int h  = nq >> 3;
        const float4 th = *(const float4*)(theta + h * 8 + dg * 4);
        #pragma unroll
        for (int i = 0; i < 4; ++i) {
            float p0 = __cosf(acc[j][i][0] + th.x);
            float p1 = p0 * __cosf(acc[j][i][1] + th.y);
            float p2 = p1 * __cosf(acc[j][i][2] + th.z);
            float p3 = p2 * __cosf(acc[j][i][3] + th.w);
            const float tot = __shfl_xor(p3, 16);
            if (dg) { p0 *= tot; p1 *= tot; p2 *= tot; p3 *= tot; }
            const int m = mbase + mw + i * 16 + col;
            const int b = m >> 10, sidx = m & (SEQ - 1);
            float* pdst = dst + (((size_t)(b * NHEAD + h) * SEQ + sidx) << 3) + dg * 4;
            *(float4*)pdst = make_float4(p0 * qs, p1 * qs, p2 * qs, p3 * qs);
        }
    }
}

// ---------------------------------------------------------------------------
// Kernel 3 (plane path): out^T = Wout * attn^T + bout.
// ---------------------------------------------------------------------------
__global__ __launch_bounds__(256, 2)
void out_mfma2_kernel(const unsigned short* __restrict__ ath, const unsigned short* __restrict__ atl,
                      const unsigned short* __restrict__ woh, const unsigned short* __restrict__ wol,
                      const float* __restrict__ bias, float* __restrict__ out)
{
    __shared__ __align__(16) unsigned char lds[65536];
    const int nb = blockIdx.x & 3;
    const int mb = blockIdx.x >> 2;
    const int nbase = nb * 128, mbase = mb * 128;

    f32x4 acc[4][4];
    #pragma unroll
    for (int j = 0; j < 4; ++j)
        #pragma unroll
        for (int i = 0; i < 4; ++i) acc[j][i] = (f32x4)(0.f);

    gemm_body_planes(woh + (size_t)nbase * EMBED, wol + (size_t)nbase * EMBED,
                     ath + (size_t)mbase * EMBED, atl + (size_t)mbase * EMBED, lds, acc);

    const int lane = threadIdx.x & 63;
    const int w    = threadIdx.x >> 6;
    const int nw   = (w & 1) * 64;
    const int mw   = (w >> 1) * 64;
    const int col  = lane & 15;
    const int lhi  = lane >> 4;

    #pragma unroll
    for (int j = 0; j < 4; ++j) {
        const int n0j = nbase + nw + j * 16 + lhi * 4;
        const float4 bs = *(const float4*)(bias + n0j);
        #pragma unroll
        for (int i = 0; i < 4; ++i) {
            const int m = mbase + mw + i * 16 + col;
            float* p = out + (size_t)m * EMBED + n0j;
            *(float4*)p = make_float4(acc[j][i][0] + bs.x, acc[j][i][1] + bs.y,
                                      acc[j][i][2] + bs.z, acc[j][i][3] + bs.w);
        }
    }
}

// ---------------------------------------------------------------------------
// Fallback GEMM machinery (round-5, verified) — used when ws_size < 44 MB.
// ---------------------------------------------------------------------------
__device__ __forceinline__ void stage_tile(const float* __restrict__ src,
                                           unsigned char* hiB, unsigned char* loB,
                                           int tid)
{
    #pragma unroll
    for (int p = 0; p < 8; ++p) {
        const int idx = p * 256 + tid;
        const int r = idx >> 4;
        const int q = idx & 15;
        const float4 v = *(const float4*)(src + (size_t)r * EMBED + q * 4);
        const unsigned int h01 = pk(v.x, v.y);
        const unsigned int h23 = pk(v.z, v.w);
        const unsigned int l01 = pk(v.x - tr_hi(v.x), v.y - tr_hi(v.y));
        const unsigned int l23 = pk(v.z - tr_hi(v.z), v.w - tr_hi(v.w));
        const int addr = r * 128 + (((q >> 1) ^ (r & 7)) << 4) + ((q & 1) << 3);
        *(uint2*)(hiB + addr) = make_uint2(h01, h23);
        *(uint2*)(loB + addr) = make_uint2(l01, l23);
    }
}

__device__ __forceinline__ void gemm_body(const float* __restrict__ A0,
                                          const float* __restrict__ B0,
                                          unsigned char* lds, f32x4 (&acc)[4][4])
{
    unsigned char* Ah = lds;
    unsigned char* Al = lds + 16384;
    unsigned char* Bh = lds + 32768;
    unsigned char* Bl = lds + 49152;
    const int tid  = threadIdx.x;
    const int lane = tid & 63;
    const int w    = tid >> 6;
    const int nw   = (w & 1) * 64;
    const int mw   = (w >> 1) * 64;
    const int col  = lane & 15;
    const int lhi  = lane >> 4;

    for (int k0 = 0; k0 < EMBED; k0 += 64) {
        stage_tile(A0 + k0, Ah, Al, tid);
        stage_tile(B0 + k0, Bh, Bl, tid);
        __syncthreads();
        #pragma unroll
        for (int s = 0; s < 2; ++s) {
            bf16x8 ah[4], al[4], bh[4], bl[4];
            #pragma unroll
            for (int j = 0; j < 4; ++j) {
                const int row = nw + j * 16 + col;
                const int addr = row * 128 + (((s * 4 + lhi) ^ (row & 7)) << 4);
                ah[j] = *(const bf16x8*)(Ah + addr);
                al[j] = *(const bf16x8*)(Al + addr);
            }
            #pragma unroll
            for (int i = 0; i < 4; ++i) {
                const int row = mw + i * 16 + col;
                const int addr = row * 128 + (((s * 4 + lhi) ^ (row & 7)) << 4);
                bh[i] = *(const bf16x8*)(Bh + addr);
                bl[i] = *(const bf16x8*)(Bl + addr);
            }
            #pragma unroll
            for (int j = 0; j < 4; ++j)
                #pragma unroll
                for (int i = 0; i < 4; ++i) {
                    acc[j][i] = __builtin_amdgcn_mfma_f32_16x16x32_bf16(ah[j], bh[i], acc[j][i], 0, 0, 0);
                    acc[j][i] = __builtin_amdgcn_mfma_f32_16x16x32_bf16(al[j], bh[i], acc[j][i], 0, 0, 0);
                    acc[j][i] = __builtin_amdgcn_mfma_f32_16x16x32_bf16(ah[j], bl[i], acc[j][i], 0, 0, 0);
                }
        }
        __syncthreads();
    }
}

__global__ __launch_bounds__(256, 2)
void qkv_mfma_kernel(const float* __restrict__ x, const float* __restrict__ W,
                     const float* __restrict__ theta,
                     float* __restrict__ qq, float* __restrict__ kq,
                     float* __restrict__ vq)
{
    __shared__ __align__(16) unsigned char lds[65536];
    const int nb = blockIdx.x % 12;
    const int mb = blockIdx.x / 12;
    const int nbase = nb * 128, mbase = mb * 128;

    f32x4 acc[4][4];
    #pragma unroll
    for (int j = 0; j < 4; ++j)
        #pragma unroll
        for (int i = 0; i < 4; ++i) acc[j][i] = (f32x4)(0.f);

    gemm_body(W + (size_t)nbase * EMBED, x + (size_t)mbase * EMBED, lds, acc);

    const int lane = threadIdx.x & 63;
    const int w    = threadIdx.x >> 6;
    const int nw   = (w & 1) * 64;
    const int mw   = (w >> 1) * 64;
    const int col  = lane & 15;
    const int lhi  = lane >> 4;
    const int dg   = lhi & 1;
    const int seg  = nbase >> 9;
    float* dst     = (seg == 0) ? qq : (seg == 1) ? kq : vq;
    const float qs = (seg == 0) ? QPRESCALE : 1.0f;
    const int nseg0 = (nbase & 511) + nw;

    #pragma unroll
    for (int j = 0; j < 4; ++j) {
        const int nq = nseg0 + j * 16 + lhi * 4;
        const int h  = nq >> 3;
        const float4 th = *(const float4*)(theta + h * 8 + dg * 4);
        #pragma unroll
        for (int i = 0; i < 4; ++i) {
            float p0 = __cosf(acc[j][i][0] + th.x);
            float p1 = p0 * __cosf(acc[j][i][1] + th.y);
            float p2 = p1 * __cosf(acc[j][i][2] + th.z);
            float p3 = p2 * __cosf(acc[j][i][3] + th.w);
            const float tot = __shfl_xor(p3, 16);
            if (dg) { p0 *= tot; p1 *= tot; p2 *= tot; p3 *= tot; }
            const int m = mbase + mw + i * 16 + col;
            const int b = m >> 10, sidx = m & (SEQ - 1);
            float* pdst = dst + (((size_t)(b * NHEAD + h) * SEQ + sidx) << 3) + dg * 4;
            *(float4*)pdst = make_float4(p0 * qs, p1 * qs, p2 * qs, p3 * qs);
        }
    }
}

__global__ __launch_bounds__(256, 2)
void out_mfma_kernel(const float* __restrict__ A, const float* __restrict__ W,
                     const float* __restrict__ bias, float* __restrict__ out)
{
    __shared__ __align__(16) unsigned char lds[65536];
    const int nb = blockIdx.x & 3;
    const int mb = blockIdx.x >> 2;
    const int nbase = nb * 128, mbase = mb * 128;

    f32x4 acc[4][4];
    #pragma unroll
    for (int j = 0; j < 4; ++j)
        #pragma unroll
        for (int i = 0; i < 4; ++i) acc[j][i] = (f32x4)(0.f);

    gemm_body(W + (size_t)nbase * EMBED, A + (size_t)mbase * EMBED, lds, acc);

    const int lane = threadIdx.x & 63;
    const int w    = threadIdx.x >> 6;
    const int nw   = (w & 1) * 64;
    const int mw   = (w >> 1) * 64;
    const int col  = lane & 15;
    const int lhi  = lane >> 4;

    #pragma unroll
    for (int j = 0; j < 4; ++j) {
        const int n0j = nbase + nw + j * 16 + lhi * 4;
        const float4 bs = *(const float4*)(bias + n0j);
        #pragma unroll
        for (int i = 0; i < 4; ++i) {
            const int m = mbase + mw + i * 16 + col;
            float* p = out + (size_t)m * EMBED + n0j;
            *(float4*)p = make_float4(acc[j][i][0] + bs.x, acc[j][i][1] + bs.y,
                                      acc[j][i][2] + bs.z, acc[j][i][3] + bs.w);
        }
    }
}

// ---------------------------------------------------------------------------
// Kernel 2 v3: MFMA attention. 512 blocks = (b,h) x 2 q-halves (2 blocks/CU,
// 4 waves/SIMD). Per k-step: 2 exact QK MFMA (d-packed split-bf16), 8 exp2,
// 1 PV MFMA (P truncated-bf16; V exact split stacked in A rows 0-7/8-15).
// Vt rows use PV-slot key order so the V fragment is ONE b128 broadcast read:
//   byte(k) = (k>>5)*64 + ((k>>2)&3)*16 + ((k>>4)&1)*8 + (k&3)*2
// ---------------------------------------------------------------------------
template<int PLANES>
__global__ __launch_bounds__(512)
void attn_mfma3_kernel(const float* __restrict__ qq, const float* __restrict__ kq,
                       const float* __restrict__ vq, float* __restrict__ attnbuf,
                       unsigned short* __restrict__ ath, unsigned short* __restrict__ atl)
{
    __shared__ __align__(16) unsigned char lds[65536];
    unsigned char* Kh = lds;            // [1024][16B] bf16x8 rows (hi)
    unsigned char* Kl = lds + 16384;    // lo
    unsigned char* Vt = lds + 32768;    // [16 rows: d0-7 hi, d0-7 lo][2048B]

    const int tid = threadIdx.x;
    const int bh  = blockIdx.x >> 1;
    const int qh  = blockIdx.x & 1;
    const size_t base = (size_t)bh * SEQ * HDIM;

    // ---- stage K split planes (16B per key row) ----
    #pragma unroll
    for (int p = 0; p < 2; ++p) {
        const int r = tid + p * 512;
        const float4 a = *(const float4*)(kq + base + (size_t)r * 8);
        const float4 b = *(const float4*)(kq + base + (size_t)r * 8 + 4);
        *(uint4*)(Kh + r * 16) = make_uint4(pk(a.x, a.y), pk(a.z, a.w),
                                            pk(b.x, b.y), pk(b.z, b.w));
        *(uint4*)(Kl + r * 16) = make_uint4(
            pk(a.x - tr_hi(a.x), a.y - tr_hi(a.y)),
            pk(a.z - tr_hi(a.z), a.w - tr_hi(a.w)),
            pk(b.x - tr_hi(b.x), b.y - tr_hi(b.y)),
            pk(b.z - tr_hi(b.z), b.w - tr_hi(b.w)));
    }
    // ---- stage V: slot-ordered transpose, split planes ----
    {
        const int k0 = tid * 2;                      // keys k0, k0+1
        const float4 va = *(const float4*)(vq + base + (size_t)k0 * 8);
        const float4 vb = *(const float4*)(vq + base + (size_t)k0 * 8 + 4);
        const float4 vc = *(const float4*)(vq + base + (size_t)k0 * 8 + 8);
        const float4 vd = *(const float4*)(vq + base + (size_t)k0 * 8 + 12);
        const float e0[8] = {va.x, va.y, va.z, va.w, vb.x, vb.y, vb.z, vb.w};
        const float e1[8] = {vc.x, vc.y, vc.z, vc.w, vd.x, vd.y, vd.z, vd.w};
        const int sb = (k0 >> 5) * 64 + ((k0 >> 2) & 3) * 16
                     + ((k0 >> 4) & 1) * 8 + (k0 & 3) * 2;
        #pragma unroll
        for (int d = 0; d < 8; ++d) {
            const float h0f = tr_hi(e0[d]), h1f = tr_hi(e1[d]);
            *(unsigned int*)(Vt + d * 2048 + sb)       = pk(h0f, h1f);
            *(unsigned int*)(Vt + (d + 8) * 2048 + sb) = pk(e0[d] - h0f, e1[d] - h1f);
        }
    }
    __syncthreads();

    const int lane = tid & 63;
    const int w    = tid >> 6;           // 0..7
    const int col  = lane & 15;
    const int g    = lane >> 4;          // slot group 0..3
    const int bb   = bh >> 6, hh = bh & 63;
    const int koff = (g >= 2) ? 16384 : 0;           // Kh for g<2, Kl for g>=2
    const int vrowbase = col * 2048;                 // A-row (= V d-plane row)

    #pragma unroll 1
    for (int it = 0; it < 4; ++it) {
        const int qrow = qh * 512 + (w * 4 + it) * 16 + col;
        const float4 qa = *(const float4*)(qq + base + (size_t)qrow * 8);
        const float4 qb = *(const float4*)(qq + base + (size_t)qrow * 8 + 4);
        B8 qhf, qlf;
        qhf.u[0] = pk(qa.x, qa.y);  qhf.u[1] = pk(qa.z, qa.w);
        qhf.u[2] = pk(qb.x, qb.y);  qhf.u[3] = pk(qb.z, qb.w);
        qlf.u[0] = pk(qa.x - tr_hi(qa.x), qa.y - tr_hi(qa.y));
        qlf.u[1] = pk(qa.z - tr_hi(qa.z), qa.w - tr_hi(qa.w));
        qlf.u[2] = pk(qb.x - tr_hi(qb.x), qb.y - tr_hi(qb.y));
        qlf.u[3] = pk(qb.z - tr_hi(qb.z), qb.w - tr_hi(qb.w));
        const bf16x8 qfrag = (g & 1) ? qlf.v : qhf.v;

        f32x4 accO = (f32x4)(0.f);
        float den = 0.f;

        #pragma unroll 2
        for (int ks = 0; ks < 32; ++ks) {
            const bf16x8 ka = *(const bf16x8*)(lds + koff + (size_t)(ks * 32 + col) * 16);
            const bf16x8 kb = *(const bf16x8*)(lds + koff + (size_t)(ks * 32 + 16 + col) * 16);
            f32x4 s0 = __builtin_amdgcn_mfma_f32_16x16x32_bf16(ka, qfrag, (f32x4)(0.f), 0, 0, 0);
            f32x4 s1 = __builtin_amdgcn_mfma_f32_16x16x32_bf16(kb, qfrag, (f32x4)(0.f), 0, 0, 0);
            const float p0 = __builtin_amdgcn_exp2f(s0[0]);
            const float p1 = __builtin_amdgcn_exp2f(s0[1]);
            const float p2 = __builtin_amdgcn_exp2f(s0[2]);
            const float p3 = __builtin_amdgcn_exp2f(s0[3]);
            const float p4 = __builtin_amdgcn_exp2f(s1[0]);
            const float p5 = __builtin_amdgcn_exp2f(s1[1]);
            const float p6 = __builtin_amdgcn_exp2f(s1[2]);
            const float p7 = __builtin_amdgcn_exp2f(s1[3]);
            den += ((p0 + p1) + (p2 + p3)) + ((p4 + p5) + (p6 + p7));
            B8 PH;
            PH.u[0] = pk(p0, p1); PH.u[1] = pk(p2, p3);
            PH.u[2] = pk(p4, p5); PH.u[3] = pk(p6, p7);
            // one contiguous 16B broadcast read: slots g*8..g*8+7 of this chunk
            const bf16x8 vf = *(const bf16x8*)(Vt + vrowbase + (ks * 4 + g) * 16);
            accO = __builtin_amdgcn_mfma_f32_16x16x32_bf16(vf, PH.v, accO, 0, 0, 0);
        }

        // reduce den across slot groups; combine Vh/Vl halves; store
        den += __shfl_xor(den, 16);
        den += __shfl_xor(den, 32);
        const float o0 = accO[0] + __shfl_xor(accO[0], 32);
        const float o1 = accO[1] + __shfl_xor(accO[1], 32);
        const float o2 = accO[2] + __shfl_xor(accO[2], 32);
        const float o3 = accO[3] + __shfl_xor(accO[3], 32);
        if (g < 2) {
            const float inv = 1.f / den;
            const float s0 = o0 * inv, s1 = o1 * inv, s2 = o2 * inv, s3 = o3 * inv;
            const size_t off = ((size_t)(bb * SEQ + qrow)) * EMBED + hh * 8 + g * 4;
            if (PLANES) {
                const float h0 = tr_hi(s0), h1 = tr_hi(s1), h2 = tr_hi(s2), h3 = tr_hi(s3);
                *(uint2*)(ath + off) = make_uint2(pk(s0, s1), pk(s2, s3));
                *(uint2*)(atl + off) = make_uint2(pk(s0 - h0, s1 - h1), pk(s2 - h2, s3 - h3));
            } else {
                *(float4*)(attnbuf + off) = make_float4(s0, s1, s2, s3);
            }
        }
    }
}

// ---------------------------------------------------------------------------
extern "C" void kernel_launch(void* const* d_in, const int* in_sizes, int n_in,
                              void* d_out, int out_size, void* d_ws, size_t ws_size,
                              hipStream_t stream)
{
    const float* x     = (const float*)d_in[0];
    const float* Wqkv  = (const float*)d_in[1];
    const float* Wout  = (const float*)d_in[2];
    const float* bout  = (const float*)d_in[3];
    const float* theta = (const float*)d_in[4];
    float* out = (float*)d_out;

    const size_t per = (size_t)4 * NHEAD * SEQ * HDIM;   // 2,097,152
    float* qq = (float*)d_ws;
    float* kq = qq + per;
    float* vq = kq + per;

    const size_t NEED = 46137344;   // 44 MB
    if (ws_size >= NEED) {
        unsigned short* xh  = (unsigned short*)(vq + per);
        unsigned short* xl  = xh + per;
        unsigned short* wqh = xl + per;
        unsigned short* wql = wqh + 786432;
        unsigned short* woh = wql + 786432;
        unsigned short* wol = woh + 262144;
        unsigned short* ath = wol + 262144;
        unsigned short* atl = ath + per;

        split3_kernel<<<dim3(3072), dim3(256), 0, stream>>>(x, Wqkv, Wout,
                                                            xh, xl, wqh, wql, woh, wol);
        qkv_mfma2_kernel<<<dim3(384), dim3(256), 0, stream>>>(xh, xl, wqh, wql, theta, qq, kq, vq);
        attn_mfma3_kernel<1><<<dim3(512), dim3(512), 0, stream>>>(qq, kq, vq, nullptr, ath, atl);
        out_mfma2_kernel<<<dim3(128), dim3(256), 0, stream>>>(ath, atl, woh, wol, bout, out);
    } else {
        float* attnbuf = vq + per;
        qkv_mfma_kernel<<<dim3(384), dim3(256), 0, stream>>>(x, Wqkv, theta, qq, kq, vq);
        attn_mfma3_kernel<0><<<dim3(512), dim3(512), 0, stream>>>(qq, kq, vq, attnbuf, nullptr, nullptr);
        out_mfma_kernel<<<dim3(128), dim3(256), 0, stream>>>(attnbuf, Wout, bout, out);
    }
}

// Round 10
// 161.594 us; speedup vs baseline: 2.1145x; 1.0090x over previous
//
#include <hip/hip_runtime.h>

#define SEQ   1024
#define EMBED 512
#define NHEAD 64
#define HDIM  8
// (1/sqrt(8)) * log2(e), folded into qq so attn uses raw exp2
#define QPRESCALE 0.5100925247059518f

typedef short bf16x8 __attribute__((ext_vector_type(8)));
typedef float f32x4  __attribute__((ext_vector_type(4)));

union B8 { bf16x8 v; unsigned int u[4]; uint2 u2[2]; };

__device__ __forceinline__ float u2f(unsigned int u) { union { unsigned int u; float f; } c; c.u = u; return c.f; }
__device__ __forceinline__ unsigned int f2u(float f) { union { float f; unsigned int u; } c; c.f = f; return c.u; }
// pack two f32 -> 2 x bf16 (truncation); element 0 in low half
__device__ __forceinline__ unsigned int pk(float e0, float e1) {
    return (f2u(e0) >> 16) | (f2u(e1) & 0xFFFF0000u);
}
__device__ __forceinline__ float tr_hi(float x) { return u2f(f2u(x) & 0xFFFF0000u); }

// ---------------------------------------------------------------------------
// Prep: split fp32 -> (hi, lo) bf16 planes, once per operand.
// ---------------------------------------------------------------------------
__global__ __launch_bounds__(256)
void split3_kernel(const float* __restrict__ x, const float* __restrict__ wqkv,
                   const float* __restrict__ wout,
                   unsigned short* __restrict__ xh, unsigned short* __restrict__ xl,
                   unsigned short* __restrict__ wqh, unsigned short* __restrict__ wql,
                   unsigned short* __restrict__ woh, unsigned short* __restrict__ wol)
{
    const int b = blockIdx.x;
    const float* src; unsigned short* hi; unsigned short* lo; int i;
    if (b < 2048)      { src = x;    hi = xh;  lo = xl;  i = b * 256 + threadIdx.x; }
    else if (b < 2816) { src = wqkv; hi = wqh; lo = wql; i = (b - 2048) * 256 + threadIdx.x; }
    else               { src = wout; hi = woh; lo = wol; i = (b - 2816) * 256 + threadIdx.x; }
    const float4 v = ((const float4*)src)[i];
    const float h0 = tr_hi(v.x), h1 = tr_hi(v.y), h2 = tr_hi(v.z), h3 = tr_hi(v.w);
    ((uint2*)hi)[i] = make_uint2(pk(v.x, v.y), pk(v.z, v.w));
    ((uint2*)lo)[i] = make_uint2(pk(v.x - h0, v.y - h1), pk(v.z - h2, v.w - h3));
}

// ---------------------------------------------------------------------------
// Plane staging for GEMMs (verified round 6).
// ---------------------------------------------------------------------------
__device__ __forceinline__ void stage_plane(const unsigned short* __restrict__ plane,
                                            int k0, unsigned char* dst, int tid)
{
    const unsigned char* src = (const unsigned char*)plane + k0 * 2;
    #pragma unroll
    for (int p = 0; p < 4; ++p) {
        const int idx = p * 256 + tid;
        const int r = idx >> 3;
        const int q = idx & 7;
        const uint4 v = *(const uint4*)(src + (size_t)r * 1024 + q * 16);
        *(uint4*)(dst + r * 128 + ((q ^ (r & 7)) << 4)) = v;
    }
}

__device__ __forceinline__ void gemm_body_planes(
    const unsigned short* __restrict__ Ahp, const unsigned short* __restrict__ Alp,
    const unsigned short* __restrict__ Bhp, const unsigned short* __restrict__ Blp,
    unsigned char* lds, f32x4 (&acc)[4][4])
{
    unsigned char* Ah = lds;
    unsigned char* Al = lds + 16384;
    unsigned char* Bh = lds + 32768;
    unsigned char* Bl = lds + 49152;
    const int tid  = threadIdx.x;
    const int lane = tid & 63;
    const int w    = tid >> 6;
    const int nw   = (w & 1) * 64;
    const int mw   = (w >> 1) * 64;
    const int col  = lane & 15;
    const int lhi  = lane >> 4;

    for (int k0 = 0; k0 < EMBED; k0 += 64) {
        stage_plane(Ahp, k0, Ah, tid);
        stage_plane(Alp, k0, Al, tid);
        stage_plane(Bhp, k0, Bh, tid);
        stage_plane(Blp, k0, Bl, tid);
        __syncthreads();
        #pragma unroll
        for (int s = 0; s < 2; ++s) {
            bf16x8 ah[4], al[4], bh[4], bl[4];
            #pragma unroll
            for (int j = 0; j < 4; ++j) {
                const int row = nw + j * 16 + col;
                const int addr = row * 128 + (((s * 4 + lhi) ^ (row & 7)) << 4);
                ah[j] = *(const bf16x8*)(Ah + addr);
                al[j] = *(const bf16x8*)(Al + addr);
            }
            #pragma unroll
            for (int i = 0; i < 4; ++i) {
                const int row = mw + i * 16 + col;
                const int addr = row * 128 + (((s * 4 + lhi) ^ (row & 7)) << 4);
                bh[i] = *(const bf16x8*)(Bh + addr);
                bl[i] = *(const bf16x8*)(Bl + addr);
            }
            #pragma unroll
            for (int j = 0; j < 4; ++j)
                #pragma unroll
                for (int i = 0; i < 4; ++i) {
                    acc[j][i] = __builtin_amdgcn_mfma_f32_16x16x32_bf16(ah[j], bh[i], acc[j][i], 0, 0, 0);
                    acc[j][i] = __builtin_amdgcn_mfma_f32_16x16x32_bf16(al[j], bh[i], acc[j][i], 0, 0, 0);
                    acc[j][i] = __builtin_amdgcn_mfma_f32_16x16x32_bf16(ah[j], bl[i], acc[j][i], 0, 0, 0);
                }
        }
        __syncthreads();
    }
}

// ---------------------------------------------------------------------------
// Kernel 1 (plane path): qkv^T = Wqkv * x^T + quantum epilogue.
// ---------------------------------------------------------------------------
__global__ __launch_bounds__(256, 2)
void qkv_mfma2_kernel(const unsigned short* __restrict__ xh, const unsigned short* __restrict__ xl,
                      const unsigned short* __restrict__ wqh, const unsigned short* __restrict__ wql,
                      const float* __restrict__ theta,
                      float* __restrict__ qq, float* __restrict__ kq,
                      float* __restrict__ vq)
{
    __shared__ __align__(16) unsigned char lds[65536];
    const int nb = blockIdx.x % 12;
    const int mb = blockIdx.x / 12;
    const int nbase = nb * 128, mbase = mb * 128;

    f32x4 acc[4][4];
    #pragma unroll
    for (int j = 0; j < 4; ++j)
        #pragma unroll
        for (int i = 0; i < 4; ++i) acc[j][i] = (f32x4)(0.f);

    gemm_body_planes(wqh + (size_t)nbase * EMBED, wql + (size_t)nbase * EMBED,
                     xh + (size_t)mbase * EMBED, xl + (size_t)mbase * EMBED, lds, acc);

    const int lane = threadIdx.x & 63;
    const int w    = threadIdx.x >> 6;
    const int nw   = (w & 1) * 64;
    const int mw   = (w >> 1) * 64;
    const int col  = lane & 15;
    const int lhi  = lane >> 4;
    const int dg   = lhi & 1;
    const int seg  = nbase >> 9;
    float* dst     = (seg == 0) ? qq : (seg == 1) ? kq : vq;
    const float qs = (seg == 0) ? QPRESCALE : 1.0f;
    const int nseg0 = (nbase & 511) + nw;

    #pragma unroll
    for (int j = 0; j < 4; ++j) {
        const int nq = nseg0 + j * 16 + lhi * 4;
        const int h  = nq >> 3;
        const float4 th = *(const float4*)(theta + h * 8 + dg * 4);
        #pragma unroll
        for (int i = 0; i < 4; ++i) {
            float p0 = __cosf(acc[j][i][0] + th.x);
            float p1 = p0 * __cosf(acc[j][i][1] + th.y);
            float p2 = p1 * __cosf(acc[j][i][2] + th.z);
            float p3 = p2 * __cosf(acc[j][i][3] + th.w);
            const float tot = __shfl_xor(p3, 16);
            if (dg) { p0 *= tot; p1 *= tot; p2 *= tot; p3 *= tot; }
            const int m = mbase + mw + i * 16 + col;
            const int b = m >> 10, sidx = m & (SEQ - 1);
            float* pdst = dst + (((size_t)(b * NHEAD + h) * SEQ + sidx) << 3) + dg * 4;
            *(float4*)pdst = make_float4(p0 * qs, p1 * qs, p2 * qs, p3 * qs);
        }
    }
}

// ---------------------------------------------------------------------------
// Kernel 3 (plane path): out^T = Wout * attn^T + bout.
// ---------------------------------------------------------------------------
__global__ __launch_bounds__(256, 2)
void out_mfma2_kernel(const unsigned short* __restrict__ ath, const unsigned short* __restrict__ atl,
                      const unsigned short* __restrict__ woh, const unsigned short* __restrict__ wol,
                      const float* __restrict__ bias, float* __restrict__ out)
{
    __shared__ __align__(16) unsigned char lds[65536];
    const int nb = blockIdx.x & 3;
    const int mb = blockIdx.x >> 2;
    const int nbase = nb * 128, mbase = mb * 128;

    f32x4 acc[4][4];
    #pragma unroll
    for (int j = 0; j < 4; ++j)
        #pragma unroll
        for (int i = 0; i < 4; ++i) acc[j][i] = (f32x4)(0.f);

    gemm_body_planes(woh + (size_t)nbase * EMBED, wol + (size_t)nbase * EMBED,
                     ath + (size_t)mbase * EMBED, atl + (size_t)mbase * EMBED, lds, acc);

    const int lane = threadIdx.x & 63;
    const int w    = threadIdx.x >> 6;
    const int nw   = (w & 1) * 64;
    const int mw   = (w >> 1) * 64;
    const int col  = lane & 15;
    const int lhi  = lane >> 4;

    #pragma unroll
    for (int j = 0; j < 4; ++j) {
        const int n0j = nbase + nw + j * 16 + lhi * 4;
        const float4 bs = *(const float4*)(bias + n0j);
        #pragma unroll
        for (int i = 0; i < 4; ++i) {
            const int m = mbase + mw + i * 16 + col;
            float* p = out + (size_t)m * EMBED + n0j;
            *(float4*)p = make_float4(acc[j][i][0] + bs.x, acc[j][i][1] + bs.y,
                                      acc[j][i][2] + bs.z, acc[j][i][3] + bs.w);
        }
    }
}

// ---------------------------------------------------------------------------
// Fallback GEMM machinery (round-5, verified) — used when ws_size < 44 MB.
// ---------------------------------------------------------------------------
__device__ __forceinline__ void stage_tile(const float* __restrict__ src,
                                           unsigned char* hiB, unsigned char* loB,
                                           int tid)
{
    #pragma unroll
    for (int p = 0; p < 8; ++p) {
        const int idx = p * 256 + tid;
        const int r = idx >> 4;
        const int q = idx & 15;
        const float4 v = *(const float4*)(src + (size_t)r * EMBED + q * 4);
        const unsigned int h01 = pk(v.x, v.y);
        const unsigned int h23 = pk(v.z, v.w);
        const unsigned int l01 = pk(v.x - tr_hi(v.x), v.y - tr_hi(v.y));
        const unsigned int l23 = pk(v.z - tr_hi(v.z), v.w - tr_hi(v.w));
        const int addr = r * 128 + (((q >> 1) ^ (r & 7)) << 4) + ((q & 1) << 3);
        *(uint2*)(hiB + addr) = make_uint2(h01, h23);
        *(uint2*)(loB + addr) = make_uint2(l01, l23);
    }
}

__device__ __forceinline__ void gemm_body(const float* __restrict__ A0,
                                          const float* __restrict__ B0,
                                          unsigned char* lds, f32x4 (&acc)[4][4])
{
    unsigned char* Ah = lds;
    unsigned char* Al = lds + 16384;
    unsigned char* Bh = lds + 32768;
    unsigned char* Bl = lds + 49152;
    const int tid  = threadIdx.x;
    const int lane = tid & 63;
    const int w    = tid >> 6;
    const int nw   = (w & 1) * 64;
    const int mw   = (w >> 1) * 64;
    const int col  = lane & 15;
    const int lhi  = lane >> 4;

    for (int k0 = 0; k0 < EMBED; k0 += 64) {
        stage_tile(A0 + k0, Ah, Al, tid);
        stage_tile(B0 + k0, Bh, Bl, tid);
        __syncthreads();
        #pragma unroll
        for (int s = 0; s < 2; ++s) {
            bf16x8 ah[4], al[4], bh[4], bl[4];
            #pragma unroll
            for (int j = 0; j < 4; ++j) {
                const int row = nw + j * 16 + col;
                const int addr = row * 128 + (((s * 4 + lhi) ^ (row & 7)) << 4);
                ah[j] = *(const bf16x8*)(Ah + addr);
                al[j] = *(const bf16x8*)(Al + addr);
            }
            #pragma unroll
            for (int i = 0; i < 4; ++i) {
                const int row = mw + i * 16 + col;
                const int addr = row * 128 + (((s * 4 + lhi) ^ (row & 7)) << 4);
                bh[i] = *(const bf16x8*)(Bh + addr);
                bl[i] = *(const bf16x8*)(Bl + addr);
            }
            #pragma unroll
            for (int j = 0; j < 4; ++j)
                #pragma unroll
                for (int i = 0; i < 4; ++i) {
                    acc[j][i] = __builtin_amdgcn_mfma_f32_16x16x32_bf16(ah[j], bh[i], acc[j][i], 0, 0, 0);
                    acc[j][i] = __builtin_amdgcn_mfma_f32_16x16x32_bf16(al[j], bh[i], acc[j][i], 0, 0, 0);
                    acc[j][i] = __builtin_amdgcn_mfma_f32_16x16x32_bf16(ah[j], bl[i], acc[j][i], 0, 0, 0);
                }
        }
        __syncthreads();
    }
}

__global__ __launch_bounds__(256, 2)
void qkv_mfma_kernel(const float* __restrict__ x, const float* __restrict__ W,
                     const float* __restrict__ theta,
                     float* __restrict__ qq, float* __restrict__ kq,
                     float* __restrict__ vq)
{
    __shared__ __align__(16) unsigned char lds[65536];
    const int nb = blockIdx.x % 12;
    const int mb = blockIdx.x / 12;
    const int nbase = nb * 128, mbase = mb * 128;

    f32x4 acc[4][4];
    #pragma unroll
    for (int j = 0; j < 4; ++j)
        #pragma unroll
        for (int i = 0; i < 4; ++i) acc[j][i] = (f32x4)(0.f);

    gemm_body(W + (size_t)nbase * EMBED, x + (size_t)mbase * EMBED, lds, acc);

    const int lane = threadIdx.x & 63;
    const int w    = threadIdx.x >> 6;
    const int nw   = (w & 1) * 64;
    const int mw   = (w >> 1) * 64;
    const int col  = lane & 15;
    const int lhi  = lane >> 4;
    const int dg   = lhi & 1;
    const int seg  = nbase >> 9;
    float* dst     = (seg == 0) ? qq : (seg == 1) ? kq : vq;
    const float qs = (seg == 0) ? QPRESCALE : 1.0f;
    const int nseg0 = (nbase & 511) + nw;

    #pragma unroll
    for (int j = 0; j < 4; ++j) {
        const int nq = nseg0 + j * 16 + lhi * 4;
        const int h  = nq >> 3;
        const float4 th = *(const float4*)(theta + h * 8 + dg * 4);
        #pragma unroll
        for (int i = 0; i < 4; ++i) {
            float p0 = __cosf(acc[j][i][0] + th.x);
            float p1 = p0 * __cosf(acc[j][i][1] + th.y);
            float p2 = p1 * __cosf(acc[j][i][2] + th.z);
            float p3 = p2 * __cosf(acc[j][i][3] + th.w);
            const float tot = __shfl_xor(p3, 16);
            if (dg) { p0 *= tot; p1 *= tot; p2 *= tot; p3 *= tot; }
            const int m = mbase + mw + i * 16 + col;
            const int b = m >> 10, sidx = m & (SEQ - 1);
            float* pdst = dst + (((size_t)(b * NHEAD + h) * SEQ + sidx) << 3) + dg * 4;
            *(float4*)pdst = make_float4(p0 * qs, p1 * qs, p2 * qs, p3 * qs);
        }
    }
}

__global__ __launch_bounds__(256, 2)
void out_mfma_kernel(const float* __restrict__ A, const float* __restrict__ W,
                     const float* __restrict__ bias, float* __restrict__ out)
{
    __shared__ __align__(16) unsigned char lds[65536];
    const int nb = blockIdx.x & 3;
    const int mb = blockIdx.x >> 2;
    const int nbase = nb * 128, mbase = mb * 128;

    f32x4 acc[4][4];
    #pragma unroll
    for (int j = 0; j < 4; ++j)
        #pragma unroll
        for (int i = 0; i < 4; ++i) acc[j][i] = (f32x4)(0.f);

    gemm_body(W + (size_t)nbase * EMBED, A + (size_t)mbase * EMBED, lds, acc);

    const int lane = threadIdx.x & 63;
    const int w    = threadIdx.x >> 6;
    const int nw   = (w & 1) * 64;
    const int mw   = (w >> 1) * 64;
    const int col  = lane & 15;
    const int lhi  = lane >> 4;

    #pragma unroll
    for (int j = 0; j < 4; ++j) {
        const int n0j = nbase + nw + j * 16 + lhi * 4;
        const float4 bs = *(const float4*)(bias + n0j);
        #pragma unroll
        for (int i = 0; i < 4; ++i) {
            const int m = mbase + mw + i * 16 + col;
            float* p = out + (size_t)m * EMBED + n0j;
            *(float4*)p = make_float4(acc[j][i][0] + bs.x, acc[j][i][1] + bs.y,
                                      acc[j][i][2] + bs.z, acc[j][i][3] + bs.w);
        }
    }
}

// ---------------------------------------------------------------------------
// Kernel 2 v4: MFMA attention = v3 + XOR-swizzled V tile.
// v3's V read was a 16-way bank conflict: addr = row*2048 + chunk*16, the
// 2048B row stride puts all 16 d-plane rows in bank 0 (14.7M conflicts/disp).
// Fix (G4): phys_chunk = chunk ^ (row&7) on BOTH write and read; rows r/r+8
// now pair 2-way per bank = free. (d+8)&7 == d&7, so one swizzled offset
// serves hi and lo planes.
// ---------------------------------------------------------------------------
template<int PLANES>
__global__ __launch_bounds__(512)
void attn_mfma4_kernel(const float* __restrict__ qq, const float* __restrict__ kq,
                       const float* __restrict__ vq, float* __restrict__ attnbuf,
                       unsigned short* __restrict__ ath, unsigned short* __restrict__ atl)
{
    __shared__ __align__(16) unsigned char lds[65536];
    unsigned char* Kh = lds;            // [1024][16B] bf16x8 rows (hi)
    unsigned char* Kl = lds + 16384;    // lo
    unsigned char* Vt = lds + 32768;    // [16 rows: d0-7 hi, d0-7 lo][2048B], swizzled

    const int tid = threadIdx.x;
    const int bh  = blockIdx.x >> 1;
    const int qh  = blockIdx.x & 1;
    const size_t base = (size_t)bh * SEQ * HDIM;

    // ---- stage K split planes (16B per key row) ----
    #pragma unroll
    for (int p = 0; p < 2; ++p) {
        const int r = tid + p * 512;
        const float4 a = *(const float4*)(kq + base + (size_t)r * 8);
        const float4 b = *(const float4*)(kq + base + (size_t)r * 8 + 4);
        *(uint4*)(Kh + r * 16) = make_uint4(pk(a.x, a.y), pk(a.z, a.w),
                                            pk(b.x, b.y), pk(b.z, b.w));
        *(uint4*)(Kl + r * 16) = make_uint4(
            pk(a.x - tr_hi(a.x), a.y - tr_hi(a.y)),
            pk(a.z - tr_hi(a.z), a.w - tr_hi(a.w)),
            pk(b.x - tr_hi(b.x), b.y - tr_hi(b.y)),
            pk(b.z - tr_hi(b.z), b.w - tr_hi(b.w)));
    }
    // ---- stage V: slot-ordered transpose, split planes, XOR-swizzled ----
    {
        const int k0 = tid * 2;                      // keys k0, k0+1
        const float4 va = *(const float4*)(vq + base + (size_t)k0 * 8);
        const float4 vb = *(const float4*)(vq + base + (size_t)k0 * 8 + 4);
        const float4 vc = *(const float4*)(vq + base + (size_t)k0 * 8 + 8);
        const float4 vd = *(const float4*)(vq + base + (size_t)k0 * 8 + 12);
        const float e0[8] = {va.x, va.y, va.z, va.w, vb.x, vb.y, vb.z, vb.w};
        const float e1[8] = {vc.x, vc.y, vc.z, vc.w, vd.x, vd.y, vd.z, vd.w};
        const int cb  = (k0 >> 5) * 4 + ((k0 >> 2) & 3);           // 16B chunk
        const int byo = ((k0 >> 4) & 1) * 8 + (k0 & 3) * 2;        // word in chunk
        #pragma unroll
        for (int d = 0; d < 8; ++d) {
            const float h0f = tr_hi(e0[d]), h1f = tr_hi(e1[d]);
            const int sb = ((cb ^ (d & 7)) << 4) + byo;            // swizzled
            *(unsigned int*)(Vt + d * 2048 + sb)       = pk(h0f, h1f);
            *(unsigned int*)(Vt + (d + 8) * 2048 + sb) = pk(e0[d] - h0f, e1[d] - h1f);
        }
    }
    __syncthreads();

    const int lane = tid & 63;
    const int w    = tid >> 6;           // 0..7
    const int col  = lane & 15;
    const int g    = lane >> 4;          // slot group 0..3
    const int bb   = bh >> 6, hh = bh & 63;
    const int koff = (g >= 2) ? 16384 : 0;           // Kh for g<2, Kl for g>=2
    const int vrowbase = col * 2048;                 // A-row (= V d-plane row)
    const int vswz = col & 7;                        // read-side swizzle

    #pragma unroll 1
    for (int it = 0; it < 4; ++it) {
        const int qrow = qh * 512 + (w * 4 + it) * 16 + col;
        const float4 qa = *(const float4*)(qq + base + (size_t)qrow * 8);
        const float4 qb = *(const float4*)(qq + base + (size_t)qrow * 8 + 4);
        B8 qhf, qlf;
        qhf.u[0] = pk(qa.x, qa.y);  qhf.u[1] = pk(qa.z, qa.w);
        qhf.u[2] = pk(qb.x, qb.y);  qhf.u[3] = pk(qb.z, qb.w);
        qlf.u[0] = pk(qa.x - tr_hi(qa.x), qa.y - tr_hi(qa.y));
        qlf.u[1] = pk(qa.z - tr_hi(qa.z), qa.w - tr_hi(qa.w));
        qlf.u[2] = pk(qb.x - tr_hi(qb.x), qb.y - tr_hi(qb.y));
        qlf.u[3] = pk(qb.z - tr_hi(qb.z), qb.w - tr_hi(qb.w));
        const bf16x8 qfrag = (g & 1) ? qlf.v : qhf.v;

        f32x4 accO = (f32x4)(0.f);
        float den = 0.f;

        #pragma unroll 2
        for (int ks = 0; ks < 32; ++ks) {
            const bf16x8 ka = *(const bf16x8*)(lds + koff + (size_t)(ks * 32 + col) * 16);
            const bf16x8 kb = *(const bf16x8*)(lds + koff + (size_t)(ks * 32 + 16 + col) * 16);
            f32x4 s0 = __builtin_amdgcn_mfma_f32_16x16x32_bf16(ka, qfrag, (f32x4)(0.f), 0, 0, 0);
            f32x4 s1 = __builtin_amdgcn_mfma_f32_16x16x32_bf16(kb, qfrag, (f32x4)(0.f), 0, 0, 0);
            const float p0 = __builtin_amdgcn_exp2f(s0[0]);
            const float p1 = __builtin_amdgcn_exp2f(s0[1]);
            const float p2 = __builtin_amdgcn_exp2f(s0[2]);
            const float p3 = __builtin_amdgcn_exp2f(s0[3]);
            const float p4 = __builtin_amdgcn_exp2f(s1[0]);
            const float p5 = __builtin_amdgcn_exp2f(s1[1]);
            const float p6 = __builtin_amdgcn_exp2f(s1[2]);
            const float p7 = __builtin_amdgcn_exp2f(s1[3]);
            den += ((p0 + p1) + (p2 + p3)) + ((p4 + p5) + (p6 + p7));
            B8 PH;
            PH.u[0] = pk(p0, p1); PH.u[1] = pk(p2, p3);
            PH.u[2] = pk(p4, p5); PH.u[3] = pk(p6, p7);
            // swizzled 16B read: slots g*8..g*8+7 of this chunk (2-way = free)
            const bf16x8 vf = *(const bf16x8*)(Vt + vrowbase + (((ks * 4 + g) ^ vswz) << 4));
            accO = __builtin_amdgcn_mfma_f32_16x16x32_bf16(vf, PH.v, accO, 0, 0, 0);
        }

        // reduce den across slot groups; combine Vh/Vl halves; store
        den += __shfl_xor(den, 16);
        den += __shfl_xor(den, 32);
        const float o0 = accO[0] + __shfl_xor(accO[0], 32);
        const float o1 = accO[1] + __shfl_xor(accO[1], 32);
        const float o2 = accO[2] + __shfl_xor(accO[2], 32);
        const float o3 = accO[3] + __shfl_xor(accO[3], 32);
        if (g < 2) {
            const float inv = 1.f / den;
            const float s0 = o0 * inv, s1 = o1 * inv, s2 = o2 * inv, s3 = o3 * inv;
            const size_t off = ((size_t)(bb * SEQ + qrow)) * EMBED + hh * 8 + g * 4;
            if (PLANES) {
                const float h0 = tr_hi(s0), h1 = tr_hi(s1), h2 = tr_hi(s2), h3 = tr_hi(s3);
                *(uint2*)(ath + off) = make_uint2(pk(s0, s1), pk(s2, s3));
                *(uint2*)(atl + off) = make_uint2(pk(s0 - h0, s1 - h1), pk(s2 - h2, s3 - h3));
            } else {
                *(float4*)(attnbuf + off) = make_float4(s0, s1, s2, s3);
            }
        }
    }
}

// ---------------------------------------------------------------------------
extern "C" void kernel_launch(void* const* d_in, const int* in_sizes, int n_in,
                              void* d_out, int out_size, void* d_ws, size_t ws_size,
                              hipStream_t stream)
{
    const float* x     = (const float*)d_in[0];
    const float* Wqkv  = (const float*)d_in[1];
    const float* Wout  = (const float*)d_in[2];
    const float* bout  = (const float*)d_in[3];
    const float* theta = (const float*)d_in[4];
    float* out = (float*)d_out;

    const size_t per = (size_t)4 * NHEAD * SEQ * HDIM;   // 2,097,152
    float* qq = (float*)d_ws;
    float* kq = qq + per;
    float* vq = kq + per;

    const size_t NEED = 46137344;   // 44 MB
    if (ws_size >= NEED) {
        unsigned short* xh  = (unsigned short*)(vq + per);
        unsigned short* xl  = xh + per;
        unsigned short* wqh = xl + per;
        unsigned short* wql = wqh + 786432;
        unsigned short* woh = wql + 786432;
        unsigned short* wol = woh + 262144;
        unsigned short* ath = wol + 262144;
        unsigned short* atl = ath + per;

        split3_kernel<<<dim3(3072), dim3(256), 0, stream>>>(x, Wqkv, Wout,
                                                            xh, xl, wqh, wql, woh, wol);
        qkv_mfma2_kernel<<<dim3(384), dim3(256), 0, stream>>>(xh, xl, wqh, wql, theta, qq, kq, vq);
        attn_mfma4_kernel<1><<<dim3(512), dim3(512), 0, stream>>>(qq, kq, vq, nullptr, ath, atl);
        out_mfma2_kernel<<<dim3(128), dim3(256), 0, stream>>>(ath, atl, woh, wol, bout, out);
    } else {
        float* attnbuf = vq + per;
        qkv_mfma_kernel<<<dim3(384), dim3(256), 0, stream>>>(x, Wqkv, theta, qq, kq, vq);
        attn_mfma4_kernel<0><<<dim3(512), dim3(512), 0, stream>>>(qq, kq, vq, attnbuf, nullptr, nullptr);
        out_mfma_kernel<<<dim3(128), dim3(256), 0, stream>>>(attnbuf, Wout, bout, out);
    }
}